// Round 12
// baseline (2286.149 us; speedup 1.0000x reference)
//
#include <hip/hip_runtime.h>
#include <stdint.h>
#include <math.h>

// ---------------------------------------------------------------------------
// Swin block, MI355X. B=32 H=W=112 C=192 NH=6 hd=32 WS=7 SS=3 -> 8192 windows,
// 49 tokens, 401408 token-rows.
// R12 = R11 with the LN-staging vector-packing bug fixed (v8u16 holds 8 u16;
// pack 6 groups x 8 channels, not 3 x 16). LN1 fused into qkv A-staging
// (gather+LN+bf16 -> LDS), LN2 fused into fc1 A-staging; ln_kern deleted.
// ---------------------------------------------------------------------------

typedef unsigned short u16;
typedef unsigned int   u32;
typedef __bf16 v8bf __attribute__((ext_vector_type(8)));
typedef float  v4f  __attribute__((ext_vector_type(4)));
typedef u16    v8u16 __attribute__((ext_vector_type(8)));
typedef u16    v4u16 __attribute__((ext_vector_type(4)));

#define MFMA16(a,b,c) __builtin_amdgcn_mfma_f32_16x16x32_bf16(a,b,c,0,0,0)

#define HSTR 77070336L          // elems per q/k/v array (8192*6*49*32)
#define QSC  0.17677669529663687f

__device__ __forceinline__ u16 f2bf(float f){
  return __builtin_bit_cast(u16, (__bf16)f);   // v_cvt RNE
}

__device__ __forceinline__ void async16(void* lds, const void* g){
  __builtin_amdgcn_global_load_lds(
      (__attribute__((address_space(1))) void*)(g),
      (__attribute__((address_space(3))) void*)(lds), 16, 0, 0);
}

// --------------------- combined weight convert (contiguous dst) ------------
// q-rows of qkv_w (first 192*192 elems) pre-scaled by hd^-0.5.
__global__ __launch_bounds__(256)
void convw(const float* __restrict__ s0, const float* __restrict__ s1,
           const float* __restrict__ s2, const float* __restrict__ s3,
           u16* __restrict__ d){
  int i = blockIdx.x * 256 + threadIdx.x;        // < 442368
  float v;
  if (i < 110592){
    v = s0[i];
    if (i < 36864) v *= QSC;
  }
  else if (i < 147456)  v = s1[i - 110592];
  else if (i < 294912)  v = s2[i - 147456];
  else                  v = s3[i - 294912];
  d[i] = f2bf(v);
}

// -------------------- fused rel-pos-bias + shift-mask table ----------------
// layout: [cls][h][m][n][lr][lg*4+r]  (matches MFMA C fragment, b128/lane)
__global__ __launch_bounds__(256)
void bmt_k(const float* __restrict__ rpb, float* __restrict__ bmt){
  int idx = blockIdx.x * 256 + threadIdx.x;      // 98304 total
  int r  = idx & 3, lg = (idx >> 2) & 3, lr = (idx >> 4) & 15;
  int n  = (idx >> 8) & 3, m = (idx >> 10) & 3;
  int t  = idx >> 12; int h = t % 6, cls = t / 6;
  int row = m*16 + lg*4 + r, col = n*16 + lr;
  float v;
  if (row >= 49 || col >= 49){
    v = -1e30f;
  } else {
    int i1 = row / 7, j1 = row - i1 * 7;
    int i2 = col / 7, j2 = col - i2 * 7;
    int ridx = (i1 - i2 + 6) * 13 + (j1 - j2 + 6);
    v = rpb[ridx * 6 + h];
    int lh1 = (cls & 2) ? (i1 < 4 ? 1 : 2) : 0;
    int lw1 = (cls & 1) ? (j1 < 4 ? 1 : 2) : 0;
    int lh2 = (cls & 2) ? (i2 < 4 ? 1 : 2) : 0;
    int lw2 = (cls & 1) ? (j2 < 4 ? 1 : 2) : 0;
    if (lh1 * 3 + lw1 != lh2 * 3 + lw2) v -= 100.f;
  }
  bmt[idx] = v;
}

// ------------------------------- GEMM (A @ W^T) ----------------------------
// BM=128, BN=64, BK=192/stage, 512 threads = 8 waves, wave = 32x32 quadrant.
// 1D grid, XCD-aligned group swizzle (56 row-blocks x ncol, col-major).
// A-staging modes:
//   EPI 0 (qkv): fp32 source (x) with shift/window GATHER + LayerNorm1
//                computed inline (4 thr/row, shfl reduce) -> bf16 sA.
//   EPI 2 (fc1): fp32 source (x1) linear + LayerNorm2 inline -> bf16 sA.
//   EPI 1,3:     bf16 A via async16 (as R8/R9).
// TRANSPOSED output: acc[n][m] = mfma(wf, af) -> D[channel][token].
template<int EPI, int LDA, int LDW>
__global__ __launch_bounds__(512)
void gemm_bt(const u16* __restrict__ A, int aRowOff,
             const u16* __restrict__ W, int K, int ncol,
             const float* __restrict__ bias,
             u16* __restrict__ ob, float* __restrict__ of,
             const float* __restrict__ xres,
             const float* __restrict__ lng, const float* __restrict__ lnb,
             int oRowOff){
  __shared__ __align__(16) u16 sA[128 * 200];
  __shared__ __align__(16) u16 sW[64 * 200];
  const int tid = threadIdx.x;
  const int wv = tid >> 6, lnn = tid & 63;
  const int lr = lnn & 15, lg = lnn >> 4;
  // group swizzle
  const int win = 56 * ncol;
  const int grp = (int)blockIdx.x / win, loc = (int)blockIdx.x - grp * win;
  const int rloc = loc % 56, cblk = loc / 56;
  const int m0   = (grp * 56 + rloc) * 128;
  const int col0 = cblk * 64;
  const int wr = wv >> 1, wc = wv & 1;

  // channel base per n-tile (4 consecutive channels per lane)
  const int chb0 = col0 + wc*32 + lg*4;
  const int chb1 = chb0 + 16;
  float4 bv0 = *(const float4*)&bias[chb0];
  float4 bv1 = *(const float4*)&bias[chb1];
  if (EPI == 0){                      // fold q-scale into bias (W pre-scaled)
    if (chb0 < 192){ bv0.x*=QSC; bv0.y*=QSC; bv0.z*=QSC; bv0.w*=QSC; }
    if (chb1 < 192){ bv1.x*=QSC; bv1.y*=QSC; bv1.z*=QSC; bv1.w*=QSC; }
  }
  v4f acc[2][2];                      // [n][m]
  acc[0][0] = acc[0][1] = (v4f){bv0.x, bv0.y, bv0.z, bv0.w};
  acc[1][0] = acc[1][1] = (v4f){bv1.x, bv1.y, bv1.z, bv1.w};

  const int rA0 = (int)((u32)tid / 25u);
  const int cA0 = tid - rA0 * 25;
  const u32 aBase = (u32)(aRowOff + m0);

  // ---------- LN-fused A staging (EPI 0/2): fp32 rows -> LN -> bf16 sA -----
  if (EPI == 0 || EPI == 2){
    const int row = tid >> 2;          // 0..127
    const int q   = tid & 3;           // quarter of the 192 channels
    const int gr  = aRowOff + m0 + row;
    const float* srcp;
    if (EPI == 0){
      u32 wdx = (u32)gr / 49u; int nn = gr - (int)wdx * 49;
      int bb = (int)(wdx >> 8); int wl2 = (int)(wdx & 255);
      int wh = wl2 >> 4, wwi = wl2 & 15;
      int ii = (int)((u32)nn / 7u), jj = nn - ii * 7;
      int th = wh * 7 + ii + 3;  if (th >= 112) th -= 112;
      int tw = wwi * 7 + jj + 3; if (tw >= 112) tw -= 112;
      srcp = xres + (u32)(bb * 12544 + th * 112 + tw) * 192u + q * 48;
    } else {
      srcp = xres + (u32)gr * 192u + q * 48;
    }
    float4 a[12];
    #pragma unroll
    for (int i = 0; i < 12; ++i) a[i] = *(const float4*)(srcp + i*4);
    float sm = 0.f, sq = 0.f;
    #pragma unroll
    for (int i = 0; i < 12; ++i){
      sm += (a[i].x + a[i].y) + (a[i].z + a[i].w);
      sq += (a[i].x*a[i].x + a[i].y*a[i].y) + (a[i].z*a[i].z + a[i].w*a[i].w);
    }
    sm += __shfl_xor(sm, 1, 64);  sq += __shfl_xor(sq, 1, 64);
    sm += __shfl_xor(sm, 2, 64);  sq += __shfl_xor(sq, 2, 64);
    float mean = sm * (1.f/192.f);
    float var  = sq * (1.f/192.f) - mean * mean;
    float rs   = rsqrtf(var + 1e-5f);
    // 6 groups of 8 channels (v8u16 = 8 x bf16 = 16B store)
    #pragma unroll
    for (int c2 = 0; c2 < 6; ++c2){
      v8u16 pk;
      #pragma unroll
      for (int i = 0; i < 2; ++i){
        const float4 gv = *(const float4*)(lng + q*48 + c2*8 + i*4);
        const float4 bv = *(const float4*)(lnb + q*48 + c2*8 + i*4);
        const float4 av = a[c2*2 + i];
        pk[i*4+0] = f2bf((av.x - mean) * rs * gv.x + bv.x);
        pk[i*4+1] = f2bf((av.y - mean) * rs * gv.y + bv.y);
        pk[i*4+2] = f2bf((av.z - mean) * rs * gv.z + bv.z);
        pk[i*4+3] = f2bf((av.w - mean) * rs * gv.w + bv.w);
      }
      *(v8u16*)&sA[row*200 + q*48 + c2*8] = pk;
    }
  }

  const int nK = K / 192;
  for (int ks = 0; ks < nK; ++ks){
    if (ks) __syncthreads();
    const int k0 = ks * 192;
    if (EPI == 1 || EPI == 3){
      // A tile: 128 rows x 25 chunks(16B) = 3200; 6 iters + 128-tail
      int ra = rA0, ca = cA0;
      #pragma unroll
      for (int it = 0; it < 6; ++it){
        int cc = (ca == 24) ? 23 : ca;
        async16((char*)sA + (size_t)(it * 512 + wv * 64) * 16,
                A + (aBase + (u32)ra) * (u32)LDA + (u32)(k0 + cc * 8));
        ra += 20; ca += 12; if (ca >= 25){ ca -= 25; ra += 1; }
      }
      if (tid < 128){
        int cc = (ca == 24) ? 23 : ca;
        async16((char*)sA + (size_t)(3072 + wv * 64) * 16,
                A + (aBase + (u32)ra) * (u32)LDA + (u32)(k0 + cc * 8));
      }
    }
    // W tile: 64 rows x 25 chunks = 1600; 3 iters + 64-tail
    int rw = rA0, cw = cA0;
    #pragma unroll
    for (int it = 0; it < 3; ++it){
      int cc = (cw == 24) ? 23 : cw;
      async16((char*)sW + (size_t)(it * 512 + wv * 64) * 16,
              W + (u32)(col0 + rw) * (u32)LDW + (u32)(k0 + cc * 8));
      rw += 20; cw += 12; if (cw >= 25){ cw -= 25; rw += 1; }
    }
    if (tid < 64){
      int cc = (cw == 24) ? 23 : cw;
      async16((char*)sW + (size_t)1536 * 16,
              W + (u32)(col0 + rw) * (u32)LDW + (u32)(k0 + cc * 8));
    }
    __syncthreads();   // drains vmcnt/lgkm -> staged data visible

    #pragma unroll
    for (int kk = 0; kk < 6; ++kk){
      v8bf af[2], wf[2];
      #pragma unroll
      for (int m = 0; m < 2; ++m)
        af[m] = *(const v8bf*)&sA[(wr*32 + m*16 + lr) * 200 + kk*32 + lg*8];
      #pragma unroll
      for (int n = 0; n < 2; ++n)
        wf[n] = *(const v8bf*)&sW[(wc*32 + n*16 + lr) * 200 + kk*32 + lg*8];
      #pragma unroll
      for (int n = 0; n < 2; ++n)
        #pragma unroll
        for (int m = 0; m < 2; ++m)
          acc[n][m] = MFMA16(wf[n], af[m], acc[n][m]);   // D[channel][token]
    }
  }

  // -------- epilogue: D row = channel (4*lg + r), D col = token (lr) -------
  if (EPI == 0){
    // addr = which*HSTR + wdx*9408 + hh*1568 + nn*32 + dd   (ob bf16)
    u32 chpart[2];
    const int chbs[2] = {chb0, chb1};
    #pragma unroll
    for (int n = 0; n < 2; ++n){
      int ch = chbs[n];
      int which = (ch >= 384) ? 2 : ((ch >= 192) ? 1 : 0);
      int rem = ch - which * 192;
      chpart[n] = (u32)which * 77070336u + (u32)((rem >> 5) * 1568 + (rem & 31));
    }
    #pragma unroll
    for (int m = 0; m < 2; ++m){
      const int t = m0 + wr*32 + m*16 + lr;
      u32 wdx = (u32)t / 49u; u32 tnn = (u32)t - wdx * 49u;
      const u32 rowpart = wdx * 9408u + tnn * 32u;
      #pragma unroll
      for (int n = 0; n < 2; ++n){
        v4u16 pk;
        pk[0] = f2bf(acc[n][m][0]); pk[1] = f2bf(acc[n][m][1]);
        pk[2] = f2bf(acc[n][m][2]); pk[3] = f2bf(acc[n][m][3]);
        *(v4u16*)&ob[chpart[n] + rowpart] = pk;
      }
    }
  } else if (EPI == 1){
    // window token -> spatial scatter + residual (fp32, float4)
    #pragma unroll
    for (int m = 0; m < 2; ++m){
      const int gr = m0 + wr*32 + m*16 + lr;
      u32 wdx = (u32)gr / 49u; int nn = gr - (int)wdx * 49;
      int bb = (int)(wdx >> 8); int wl2 = (int)(wdx & 255);
      int wh = wl2 >> 4, wwi = wl2 & 15;
      int ii = (int)((u32)nn / 7u), jj = nn - ii * 7;
      int th = wh * 7 + ii + 3;  if (th >= 112) th -= 112;
      int tw = wwi * 7 + jj + 3; if (tw >= 112) tw -= 112;
      u32 adr = (u32)(bb * 12544 + th * 112 + tw) * 192u;
      #pragma unroll
      for (int n = 0; n < 2; ++n){
        u32 a2 = adr + (u32)(n ? chb1 : chb0);
        float4 xv = *(const float4*)&xres[a2];
        float4 ov = {xv.x + acc[n][m][0], xv.y + acc[n][m][1],
                     xv.z + acc[n][m][2], xv.w + acc[n][m][3]};
        *(float4*)&of[a2] = ov;
      }
    }
  } else if (EPI == 3){
    // rows already spatial -> linear += (fp32, float4)
    #pragma unroll
    for (int m = 0; m < 2; ++m){
      const u32 base = (u32)(oRowOff + m0 + wr*32 + m*16 + lr) * 192u;
      #pragma unroll
      for (int n = 0; n < 2; ++n){
        u32 a2 = base + (u32)(n ? chb1 : chb0);
        float4 xv = *(const float4*)&of[a2];
        float4 ov = {xv.x + acc[n][m][0], xv.y + acc[n][m][1],
                     xv.z + acc[n][m][2], xv.w + acc[n][m][3]};
        *(float4*)&of[a2] = ov;
      }
    }
  } else {  // EPI == 2: gelu -> h1 bf16, row-linear, packed 8B
    #pragma unroll
    for (int m = 0; m < 2; ++m){
      const u32 base = (u32)(m0 + wr*32 + m*16 + lr) * 768u;
      #pragma unroll
      for (int n = 0; n < 2; ++n){
        v4u16 pk;
        #pragma unroll
        for (int r = 0; r < 4; ++r){
          float v = acc[n][m][r];
          pk[r] = f2bf(0.5f * v * (1.0f + erff(v * 0.7071067811865475f)));
        }
        *(v4u16*)&ob[base + (u32)(n ? chb1 : chb0)] = pk;
      }
    }
  }
}

// ------------------------------- attention (R8 version) --------------------
// one wave per (window, head); 4 waves / block.  49 padded to 64.
// Scores bounded -> no max pass; masked (-100) / pad (-1e30) underflow to 0.
__global__ __launch_bounds__(256, 4)
void attn_k(const u16* __restrict__ qkv, const float* __restrict__ bmt,
            u16* __restrict__ aout){
  __shared__ __align__(16) u16 plds[4][64 * 64];   // 32 KB total
  const int wv = threadIdx.x >> 6, lnn = threadIdx.x & 63;
  const int lr = lnn & 15, lg = lnn >> 4;
  const u32 gid = (u32)blockIdx.x * 4u + (u32)wv;   // < 49152
  const u32 w = gid / 6u; const int h = (int)(gid - w * 6u);
  const u16* qb = qkv + (size_t)gid * 1568;
  const u16* kb = qb + HSTR;
  const u16* vb = kb + HSTR;

  // C-init = bias+mask table (b128 per lane, L2/L3-resident)
  const int wl = (int)(w & 255);
  const int cls = (((wl >> 4) == 15) ? 2 : 0) | (((wl & 15) == 15) ? 1 : 0);
  const float* bmv = bmt + ((u32)(cls * 6 + h) << 12);
  v4f s[4][4];
  #pragma unroll
  for (int m = 0; m < 4; ++m)
    #pragma unroll
    for (int n = 0; n < 4; ++n)
      s[m][n] = *(const v4f*)&bmv[(u32)(((m*4 + n)*16 + lr)*16 + lg*4)];

  // Q.K^T on top of bias
  v8bf aq[4], bk4[4];
  #pragma unroll
  for (int m = 0; m < 4; ++m) aq[m]  = *(const v8bf*)(qb + (m*16 + lr)*32 + lg*8);
  #pragma unroll
  for (int n = 0; n < 4; ++n) bk4[n] = *(const v8bf*)(kb + (n*16 + lr)*32 + lg*8);
  #pragma unroll
  for (int m = 0; m < 4; ++m)
    #pragma unroll
    for (int n = 0; n < 4; ++n) s[m][n] = MFMA16(aq[m], bk4[n], s[m][n]);

  // V fragments from global, k-permuted (pads multiply P==0 -> harmless)
  v8u16 bvu[2][2];
  #pragma unroll
  for (int n2 = 0; n2 < 2; ++n2)
    #pragma unroll
    for (int ksi = 0; ksi < 2; ++ksi)
      #pragma unroll
      for (int e = 0; e < 8; ++e){
        int kp = ksi * 32 + lg * 8 + e;
        int t  = (kp >> 2) + (kp & 3) * 16;
        bvu[n2][ksi][e] = vb[(u32)(t * 32 + n2 * 16 + lr)];
      }

  // P = exp(s), packed store (pos = lr*4+n), XOR-swizzled rows
  #pragma unroll
  for (int m = 0; m < 4; ++m)
    #pragma unroll
    for (int r = 0; r < 4; ++r){
      int row = m*16 + lg*4 + r;
      v4u16 pk;
      pk[0] = f2bf(__expf(s[m][0][r]));
      pk[1] = f2bf(__expf(s[m][1][r]));
      pk[2] = f2bf(__expf(s[m][2][r]));
      pk[3] = f2bf(__expf(s[m][3][r]));
      *(v4u16*)((char*)&plds[wv][0] + row*128 + ((lr*8) ^ ((row & 7) << 4))) = pk;
    }

  v8bf pa[4][2];
  #pragma unroll
  for (int m2 = 0; m2 < 4; ++m2)
    #pragma unroll
    for (int ksi = 0; ksi < 2; ++ksi){
      int row2 = m2*16 + lr;
      pa[m2][ksi] = *(const v8bf*)((const char*)&plds[wv][0] + row2*128 +
                                   ((ksi*64 + lg*16) ^ ((row2 & 7) << 4)));
    }

  // ones B-frag (col 0 only) for row-sums
  v8u16 onesu;
  #pragma unroll
  for (int e = 0; e < 8; ++e) onesu[e] = (lr == 0) ? (u16)0x3F80 : (u16)0;
  const v8bf onesf = __builtin_bit_cast(v8bf, onesu);

  const v4f zf = {0.f, 0.f, 0.f, 0.f};
  v4f o2[4][2], sacc[4];
  #pragma unroll
  for (int m2 = 0; m2 < 4; ++m2){
    o2[m2][0] = zf; o2[m2][1] = zf; sacc[m2] = zf;
  }
  #pragma unroll
  for (int ksi = 0; ksi < 2; ++ksi)
    #pragma unroll
    for (int m2 = 0; m2 < 4; ++m2){
      o2[m2][0] = MFMA16(pa[m2][ksi], __builtin_bit_cast(v8bf, bvu[0][ksi]), o2[m2][0]);
      o2[m2][1] = MFMA16(pa[m2][ksi], __builtin_bit_cast(v8bf, bvu[1][ksi]), o2[m2][1]);
      sacc[m2]  = MFMA16(pa[m2][ksi], onesf, sacc[m2]);
    }

  float inv[4][4];
  #pragma unroll
  for (int m2 = 0; m2 < 4; ++m2)
    #pragma unroll
    for (int r = 0; r < 4; ++r)
      inv[m2][r] = 1.0f / __shfl(sacc[m2][r], lnn & 48, 64);

  #pragma unroll
  for (int m2 = 0; m2 < 4; ++m2){
    #pragma unroll
    for (int n2 = 0; n2 < 2; ++n2){
      #pragma unroll
      for (int r = 0; r < 4; ++r){
        int row = m2*16 + lg*4 + r;
        if (row < 49){
          float val = o2[m2][n2][r] * inv[m2][r];
          aout[(w * 49u + (u32)row) * 192u + (u32)(h*32 + n2*16 + lr)] = f2bf(val);
        }
      }
    }
  }
}

// ------------------------------ launcher -----------------------------------
extern "C" void kernel_launch(void* const* d_in, const int* in_sizes, int n_in,
                              void* d_out, int out_size, void* d_ws, size_t ws_size,
                              hipStream_t stream){
  const float* x     = (const float*)d_in[0];
  const float* n1g   = (const float*)d_in[1];
  const float* n1b   = (const float*)d_in[2];
  const float* qkvw  = (const float*)d_in[3];
  const float* qkvb  = (const float*)d_in[4];
  const float* rpb   = (const float*)d_in[5];
  const float* projw = (const float*)d_in[6];
  const float* projb = (const float*)d_in[7];
  const float* n2g   = (const float*)d_in[8];
  const float* n2b   = (const float*)d_in[9];
  const float* fc1w  = (const float*)d_in[10];
  const float* fc1b  = (const float*)d_in[11];
  const float* fc2w  = (const float*)d_in[12];
  const float* fc2b  = (const float*)d_in[13];
  float* out = (float*)d_out;

  char* ws  = (char*)d_ws;
  u16* bufA = (u16*)ws;                       // qkv 462MB -> h1 chunks
  u16* bufB = (u16*)(ws + 462422016L);        // attn_out
  u16* wq   = (u16*)(ws + 616562688L);
  u16* wp   = wq + 110592;
  u16* w1   = wp + 36864;
  u16* w2   = w1 + 147456;
  float* bmt = (float*)d_out;   // 98304 floats, consumed by attn before proj

  convw<<<1728, 256, 0, stream>>>(qkvw, projw, fc1w, fc2w, wq);
  bmt_k<<<384, 256, 0, stream>>>(rpb, bmt);

  // qkv: LN1 fused into A-staging (gather from x). grid = 3136*9 swizzled
  gemm_bt<0, 192, 192><<<3136*9, 512, 0, stream>>>(nullptr, 0, wq, 192, 9,
                                                   qkvb, bufA, nullptr,
                                                   x, n1g, n1b, 0);
  // windowed attention
  attn_k<<<12288, 256, 0, stream>>>(bufA, bmt, bufB);
  // proj + scatter + residual -> d_out (spatial order)
  gemm_bt<1, 192, 192><<<3136*3, 512, 0, stream>>>(bufB, 0, wp, 192, 3,
                                                   projb, nullptr, out,
                                                   x, nullptr, nullptr, 0);
  // MLP in 2 token-chunks; fc1 has LN2 fused (reads x1=out fp32 linear)
  for (int c = 0; c < 2; ++c){
    int off = c * 200704;
    gemm_bt<2, 192, 192><<<1568*12, 512, 0, stream>>>(nullptr, off, w1, 192, 12,
                                                      fc1b, bufA, nullptr,
                                                      out, n2g, n2b, 0);
    gemm_bt<3, 768, 768><<<1568*3, 512, 0, stream>>>(bufA, 0, w2, 768, 3,
                                                     fc2b, nullptr, out,
                                                     nullptr, nullptr, nullptr, off);
  }
}

// Round 13
// 1432.479 us; speedup vs baseline: 1.5959x; 1.5959x over previous
//
#include <hip/hip_runtime.h>
#include <stdint.h>
#include <math.h>

// ---------------------------------------------------------------------------
// Swin block, MI355X. B=32 H=W=112 C=192 NH=6 hd=32 WS=7 SS=3 -> 8192 windows,
// 49 tokens, 401408 token-rows.
// R13 = best-of ledger: R9 gemm (transposed D, packed stores) + R8 attn
// (coalesced scalar-run stores) + separate LN passes. LN-fusion (R11/12)
// reverted: it serialized A-staging (async16 -> sync load/reduce chain) and
// doubled A fetch (fp32 x 9 col-blocks). R10 (A-direct-global) also stays
// reverted (latency-bound).
// ---------------------------------------------------------------------------

typedef unsigned short u16;
typedef unsigned int   u32;
typedef __bf16 v8bf __attribute__((ext_vector_type(8)));
typedef float  v4f  __attribute__((ext_vector_type(4)));
typedef u16    v8u16 __attribute__((ext_vector_type(8)));
typedef u16    v4u16 __attribute__((ext_vector_type(4)));

#define MFMA16(a,b,c) __builtin_amdgcn_mfma_f32_16x16x32_bf16(a,b,c,0,0,0)

#define HSTR 77070336L          // elems per q/k/v array (8192*6*49*32)
#define QSC  0.17677669529663687f

__device__ __forceinline__ u16 f2bf(float f){
  return __builtin_bit_cast(u16, (__bf16)f);   // v_cvt RNE
}

__device__ __forceinline__ void async16(void* lds, const void* g){
  __builtin_amdgcn_global_load_lds(
      (__attribute__((address_space(1))) void*)(g),
      (__attribute__((address_space(3))) void*)(lds), 16, 0, 0);
}

// --------------------- combined weight convert (contiguous dst) ------------
// q-rows of qkv_w (first 192*192 elems) pre-scaled by hd^-0.5.
__global__ __launch_bounds__(256)
void convw(const float* __restrict__ s0, const float* __restrict__ s1,
           const float* __restrict__ s2, const float* __restrict__ s3,
           u16* __restrict__ d){
  int i = blockIdx.x * 256 + threadIdx.x;        // < 442368
  float v;
  if (i < 110592){
    v = s0[i];
    if (i < 36864) v *= QSC;
  }
  else if (i < 147456)  v = s1[i - 110592];
  else if (i < 294912)  v = s2[i - 147456];
  else                  v = s3[i - 294912];
  d[i] = f2bf(v);
}

// -------------------- fused rel-pos-bias + shift-mask table ----------------
// layout: [cls][h][m][n][lr][lg*4+r]  (matches MFMA C fragment, b128/lane)
__global__ __launch_bounds__(256)
void bmt_k(const float* __restrict__ rpb, float* __restrict__ bmt){
  int idx = blockIdx.x * 256 + threadIdx.x;      // 98304 total
  int r  = idx & 3, lg = (idx >> 2) & 3, lr = (idx >> 4) & 15;
  int n  = (idx >> 8) & 3, m = (idx >> 10) & 3;
  int t  = idx >> 12; int h = t % 6, cls = t / 6;
  int row = m*16 + lg*4 + r, col = n*16 + lr;
  float v;
  if (row >= 49 || col >= 49){
    v = -1e30f;
  } else {
    int i1 = row / 7, j1 = row - i1 * 7;
    int i2 = col / 7, j2 = col - i2 * 7;
    int ridx = (i1 - i2 + 6) * 13 + (j1 - j2 + 6);
    v = rpb[ridx * 6 + h];
    int lh1 = (cls & 2) ? (i1 < 4 ? 1 : 2) : 0;
    int lw1 = (cls & 1) ? (j1 < 4 ? 1 : 2) : 0;
    int lh2 = (cls & 2) ? (i2 < 4 ? 1 : 2) : 0;
    int lw2 = (cls & 1) ? (j2 < 4 ? 1 : 2) : 0;
    if (lh1 * 3 + lw1 != lh2 * 3 + lw2) v -= 100.f;
  }
  bmt[idx] = v;
}

// ----------------------- LayerNorm (optionally gathered) -------------------
// 16 lanes per token, 4 tokens per wave; lane handles 12 channels (3 float4).
template<bool GATHER>
__global__ __launch_bounds__(256)
void ln_kern(const float* __restrict__ x, const float* __restrict__ g,
             const float* __restrict__ b, u16* __restrict__ o){
  const int ts  = threadIdx.x >> 4;
  const int l16 = threadIdx.x & 15;
  const int r   = blockIdx.x * 16 + ts;          // < 401408
  const float* src;
  if (GATHER){
    u32 wdx = (u32)r / 49u; int nn = r - (int)wdx * 49;
    int bb = (int)(wdx >> 8); int wl = (int)(wdx & 255);
    int wh = wl >> 4, wwi = wl & 15;
    int ii = (int)((u32)nn / 7u), jj = nn - ii * 7;
    int th = wh * 7 + ii + 3;  if (th >= 112) th -= 112;
    int tw = wwi * 7 + jj + 3; if (tw >= 112) tw -= 112;
    src = x + (u32)(bb * 12544 + th * 112 + tw) * 192u;
  } else {
    src = x + (u32)r * 192u;
  }
  const float4 a0 = *(const float4*)(src + l16*12);
  const float4 a1 = *(const float4*)(src + l16*12 + 4);
  const float4 a2 = *(const float4*)(src + l16*12 + 8);
  float sm = ((a0.x+a0.y)+(a0.z+a0.w)) + ((a1.x+a1.y)+(a1.z+a1.w))
           + ((a2.x+a2.y)+(a2.z+a2.w));
  float sq = ((a0.x*a0.x+a0.y*a0.y)+(a0.z*a0.z+a0.w*a0.w))
           + ((a1.x*a1.x+a1.y*a1.y)+(a1.z*a1.z+a1.w*a1.w))
           + ((a2.x*a2.x+a2.y*a2.y)+(a2.z*a2.z+a2.w*a2.w));
  #pragma unroll
  for (int d = 1; d < 16; d <<= 1){
    sm += __shfl_xor(sm, d, 64);
    sq += __shfl_xor(sq, d, 64);
  }
  float mean = sm * (1.f/192.f);
  float var  = sq * (1.f/192.f) - mean * mean;
  float rs   = rsqrtf(var + 1e-5f);
  const float4 g0 = *(const float4*)(g + l16*12);
  const float4 g1 = *(const float4*)(g + l16*12 + 4);
  const float4 g2 = *(const float4*)(g + l16*12 + 8);
  const float4 b0 = *(const float4*)(b + l16*12);
  const float4 b1 = *(const float4*)(b + l16*12 + 4);
  const float4 b2 = *(const float4*)(b + l16*12 + 8);
  u16* dst = o + (u32)r * 192u + l16 * 12;
  v4u16 w0, w1, w2;
  w0[0]=f2bf((a0.x-mean)*rs*g0.x+b0.x); w0[1]=f2bf((a0.y-mean)*rs*g0.y+b0.y);
  w0[2]=f2bf((a0.z-mean)*rs*g0.z+b0.z); w0[3]=f2bf((a0.w-mean)*rs*g0.w+b0.w);
  w1[0]=f2bf((a1.x-mean)*rs*g1.x+b1.x); w1[1]=f2bf((a1.y-mean)*rs*g1.y+b1.y);
  w1[2]=f2bf((a1.z-mean)*rs*g1.z+b1.z); w1[3]=f2bf((a1.w-mean)*rs*g1.w+b1.w);
  w2[0]=f2bf((a2.x-mean)*rs*g2.x+b2.x); w2[1]=f2bf((a2.y-mean)*rs*g2.y+b2.y);
  w2[2]=f2bf((a2.z-mean)*rs*g2.z+b2.z); w2[3]=f2bf((a2.w-mean)*rs*g2.w+b2.w);
  *(v4u16*)(dst)     = w0;
  *(v4u16*)(dst + 4) = w1;
  *(v4u16*)(dst + 8) = w2;
}

// ------------------------------- GEMM (A @ W^T) ----------------------------
// BM=128, BN=64, BK=192/stage, 512 threads = 8 waves, wave = 32x32 quadrant.
// 1D grid, XCD-aligned group swizzle. TRANSPOSED output: acc[n][m] =
// mfma(wf, af) -> D[channel][token]; packed 8B/16B stores.
// EPI: 0 qkv permuted store | 1 proj scatter+residual (window->spatial)
//      2 fc1 gelu (linear)  | 3 fc2 linear += (rows already spatial)
template<int EPI, int LDA, int LDW>
__global__ __launch_bounds__(512)
void gemm_bt(const u16* __restrict__ A, int aRowOff,
             const u16* __restrict__ W, int K, int ncol,
             const float* __restrict__ bias,
             u16* __restrict__ ob, float* __restrict__ of,
             const float* __restrict__ xres, int oRowOff){
  __shared__ __align__(16) u16 sA[128 * 200];
  __shared__ __align__(16) u16 sW[64 * 200];
  const int tid = threadIdx.x;
  const int wv = tid >> 6, lnn = tid & 63;
  const int lr = lnn & 15, lg = lnn >> 4;
  // group swizzle
  const int win = 56 * ncol;
  const int grp = (int)blockIdx.x / win, loc = (int)blockIdx.x - grp * win;
  const int rloc = loc % 56, cblk = loc / 56;
  const int m0   = (grp * 56 + rloc) * 128;
  const int col0 = cblk * 64;
  const int wr = wv >> 1, wc = wv & 1;

  // channel base per n-tile (4 consecutive channels per lane)
  const int chb0 = col0 + wc*32 + lg*4;
  const int chb1 = chb0 + 16;
  float4 bv0 = *(const float4*)&bias[chb0];
  float4 bv1 = *(const float4*)&bias[chb1];
  if (EPI == 0){                      // fold q-scale into bias (W pre-scaled)
    if (chb0 < 192){ bv0.x*=QSC; bv0.y*=QSC; bv0.z*=QSC; bv0.w*=QSC; }
    if (chb1 < 192){ bv1.x*=QSC; bv1.y*=QSC; bv1.z*=QSC; bv1.w*=QSC; }
  }
  v4f acc[2][2];                      // [n][m]
  acc[0][0] = acc[0][1] = (v4f){bv0.x, bv0.y, bv0.z, bv0.w};
  acc[1][0] = acc[1][1] = (v4f){bv1.x, bv1.y, bv1.z, bv1.w};

  const int rA0 = (int)((u32)tid / 25u);
  const int cA0 = tid - rA0 * 25;
  const u32 aBase = (u32)(aRowOff + m0);
  const int nK = K / 192;
  for (int ks = 0; ks < nK; ++ks){
    if (ks) __syncthreads();
    const int k0 = ks * 192;
    // A tile: 128 rows x 25 chunks(16B) = 3200; 6 iters + 128-tail
    int ra = rA0, ca = cA0;
    #pragma unroll
    for (int it = 0; it < 6; ++it){
      int cc = (ca == 24) ? 23 : ca;
      async16((char*)sA + (size_t)(it * 512 + wv * 64) * 16,
              A + (aBase + (u32)ra) * (u32)LDA + (u32)(k0 + cc * 8));
      ra += 20; ca += 12; if (ca >= 25){ ca -= 25; ra += 1; }
    }
    if (tid < 128){
      int cc = (ca == 24) ? 23 : ca;
      async16((char*)sA + (size_t)(3072 + wv * 64) * 16,
              A + (aBase + (u32)ra) * (u32)LDA + (u32)(k0 + cc * 8));
    }
    // W tile: 64 rows x 25 chunks = 1600; 3 iters + 64-tail
    int rw = rA0, cw = cA0;
    #pragma unroll
    for (int it = 0; it < 3; ++it){
      int cc = (cw == 24) ? 23 : cw;
      async16((char*)sW + (size_t)(it * 512 + wv * 64) * 16,
              W + (u32)(col0 + rw) * (u32)LDW + (u32)(k0 + cc * 8));
      rw += 20; cw += 12; if (cw >= 25){ cw -= 25; rw += 1; }
    }
    if (tid < 64){
      int cc = (cw == 24) ? 23 : cw;
      async16((char*)sW + (size_t)1536 * 16,
              W + (u32)(col0 + rw) * (u32)LDW + (u32)(k0 + cc * 8));
    }
    __syncthreads();   // drains vmcnt(0) -> staged data visible

    #pragma unroll
    for (int kk = 0; kk < 6; ++kk){
      v8bf af[2], wf[2];
      #pragma unroll
      for (int m = 0; m < 2; ++m)
        af[m] = *(const v8bf*)&sA[(wr*32 + m*16 + lr) * 200 + kk*32 + lg*8];
      #pragma unroll
      for (int n = 0; n < 2; ++n)
        wf[n] = *(const v8bf*)&sW[(wc*32 + n*16 + lr) * 200 + kk*32 + lg*8];
      #pragma unroll
      for (int n = 0; n < 2; ++n)
        #pragma unroll
        for (int m = 0; m < 2; ++m)
          acc[n][m] = MFMA16(wf[n], af[m], acc[n][m]);   // D[channel][token]
    }
  }

  // -------- epilogue: D row = channel (4*lg + r), D col = token (lr) -------
  if (EPI == 0){
    // addr = which*HSTR + wdx*9408 + hh*1568 + nn*32 + dd   (ob bf16)
    u32 chpart[2];
    const int chbs[2] = {chb0, chb1};
    #pragma unroll
    for (int n = 0; n < 2; ++n){
      int ch = chbs[n];
      int which = (ch >= 384) ? 2 : ((ch >= 192) ? 1 : 0);
      int rem = ch - which * 192;
      chpart[n] = (u32)which * 77070336u + (u32)((rem >> 5) * 1568 + (rem & 31));
    }
    #pragma unroll
    for (int m = 0; m < 2; ++m){
      const int t = m0 + wr*32 + m*16 + lr;
      u32 wdx = (u32)t / 49u; u32 tnn = (u32)t - wdx * 49u;
      const u32 rowpart = wdx * 9408u + tnn * 32u;
      #pragma unroll
      for (int n = 0; n < 2; ++n){
        v4u16 pk;
        pk[0] = f2bf(acc[n][m][0]); pk[1] = f2bf(acc[n][m][1]);
        pk[2] = f2bf(acc[n][m][2]); pk[3] = f2bf(acc[n][m][3]);
        *(v4u16*)&ob[chpart[n] + rowpart] = pk;
      }
    }
  } else if (EPI == 1){
    // window token -> spatial scatter + residual (fp32, float4)
    #pragma unroll
    for (int m = 0; m < 2; ++m){
      const int gr = m0 + wr*32 + m*16 + lr;
      u32 wdx = (u32)gr / 49u; int nn = gr - (int)wdx * 49;
      int bb = (int)(wdx >> 8); int wl = (int)(wdx & 255);
      int wh = wl >> 4, wwi = wl & 15;
      int ii = (int)((u32)nn / 7u), jj = nn - ii * 7;
      int th = wh * 7 + ii + 3;  if (th >= 112) th -= 112;
      int tw = wwi * 7 + jj + 3; if (tw >= 112) tw -= 112;
      u32 adr = (u32)(bb * 12544 + th * 112 + tw) * 192u;
      #pragma unroll
      for (int n = 0; n < 2; ++n){
        u32 a2 = adr + (u32)(n ? chb1 : chb0);
        float4 xv = *(const float4*)&xres[a2];
        float4 ov = {xv.x + acc[n][m][0], xv.y + acc[n][m][1],
                     xv.z + acc[n][m][2], xv.w + acc[n][m][3]};
        *(float4*)&of[a2] = ov;
      }
    }
  } else if (EPI == 3){
    // rows already spatial -> linear += (fp32, float4)
    #pragma unroll
    for (int m = 0; m < 2; ++m){
      const u32 base = (u32)(oRowOff + m0 + wr*32 + m*16 + lr) * 192u;
      #pragma unroll
      for (int n = 0; n < 2; ++n){
        u32 a2 = base + (u32)(n ? chb1 : chb0);
        float4 xv = *(const float4*)&of[a2];
        float4 ov = {xv.x + acc[n][m][0], xv.y + acc[n][m][1],
                     xv.z + acc[n][m][2], xv.w + acc[n][m][3]};
        *(float4*)&of[a2] = ov;
      }
    }
  } else {  // EPI == 2: gelu -> h1 bf16, row-linear, packed 8B
    #pragma unroll
    for (int m = 0; m < 2; ++m){
      const u32 base = (u32)(m0 + wr*32 + m*16 + lr) * 768u;
      #pragma unroll
      for (int n = 0; n < 2; ++n){
        v4u16 pk;
        #pragma unroll
        for (int r = 0; r < 4; ++r){
          float v = acc[n][m][r];
          pk[r] = f2bf(0.5f * v * (1.0f + erff(v * 0.7071067811865475f)));
        }
        *(v4u16*)&ob[base + (u32)(n ? chb1 : chb0)] = pk;
      }
    }
  }
}

// ------------------------------- attention (R8 version) --------------------
// one wave per (window, head); 4 waves / block.  49 padded to 64.
// Scores bounded -> no max pass; masked (-100) / pad (-1e30) underflow to 0.
__global__ __launch_bounds__(256, 4)
void attn_k(const u16* __restrict__ qkv, const float* __restrict__ bmt,
            u16* __restrict__ aout){
  __shared__ __align__(16) u16 plds[4][64 * 64];   // 32 KB total
  const int wv = threadIdx.x >> 6, lnn = threadIdx.x & 63;
  const int lr = lnn & 15, lg = lnn >> 4;
  const u32 gid = (u32)blockIdx.x * 4u + (u32)wv;   // < 49152
  const u32 w = gid / 6u; const int h = (int)(gid - w * 6u);
  const u16* qb = qkv + (size_t)gid * 1568;
  const u16* kb = qb + HSTR;
  const u16* vb = kb + HSTR;

  // C-init = bias+mask table (b128 per lane, L2/L3-resident)
  const int wl = (int)(w & 255);
  const int cls = (((wl >> 4) == 15) ? 2 : 0) | (((wl & 15) == 15) ? 1 : 0);
  const float* bmv = bmt + ((u32)(cls * 6 + h) << 12);
  v4f s[4][4];
  #pragma unroll
  for (int m = 0; m < 4; ++m)
    #pragma unroll
    for (int n = 0; n < 4; ++n)
      s[m][n] = *(const v4f*)&bmv[(u32)(((m*4 + n)*16 + lr)*16 + lg*4)];

  // Q.K^T on top of bias
  v8bf aq[4], bk4[4];
  #pragma unroll
  for (int m = 0; m < 4; ++m) aq[m]  = *(const v8bf*)(qb + (m*16 + lr)*32 + lg*8);
  #pragma unroll
  for (int n = 0; n < 4; ++n) bk4[n] = *(const v8bf*)(kb + (n*16 + lr)*32 + lg*8);
  #pragma unroll
  for (int m = 0; m < 4; ++m)
    #pragma unroll
    for (int n = 0; n < 4; ++n) s[m][n] = MFMA16(aq[m], bk4[n], s[m][n]);

  // V fragments from global, k-permuted (pads multiply P==0 -> harmless)
  v8u16 bvu[2][2];
  #pragma unroll
  for (int n2 = 0; n2 < 2; ++n2)
    #pragma unroll
    for (int ksi = 0; ksi < 2; ++ksi)
      #pragma unroll
      for (int e = 0; e < 8; ++e){
        int kp = ksi * 32 + lg * 8 + e;
        int t  = (kp >> 2) + (kp & 3) * 16;
        bvu[n2][ksi][e] = vb[(u32)(t * 32 + n2 * 16 + lr)];
      }

  // P = exp(s), packed store (pos = lr*4+n), XOR-swizzled rows
  #pragma unroll
  for (int m = 0; m < 4; ++m)
    #pragma unroll
    for (int r = 0; r < 4; ++r){
      int row = m*16 + lg*4 + r;
      v4u16 pk;
      pk[0] = f2bf(__expf(s[m][0][r]));
      pk[1] = f2bf(__expf(s[m][1][r]));
      pk[2] = f2bf(__expf(s[m][2][r]));
      pk[3] = f2bf(__expf(s[m][3][r]));
      *(v4u16*)((char*)&plds[wv][0] + row*128 + ((lr*8) ^ ((row & 7) << 4))) = pk;
    }

  v8bf pa[4][2];
  #pragma unroll
  for (int m2 = 0; m2 < 4; ++m2)
    #pragma unroll
    for (int ksi = 0; ksi < 2; ++ksi){
      int row2 = m2*16 + lr;
      pa[m2][ksi] = *(const v8bf*)((const char*)&plds[wv][0] + row2*128 +
                                   ((ksi*64 + lg*16) ^ ((row2 & 7) << 4)));
    }

  // ones B-frag (col 0 only) for row-sums
  v8u16 onesu;
  #pragma unroll
  for (int e = 0; e < 8; ++e) onesu[e] = (lr == 0) ? (u16)0x3F80 : (u16)0;
  const v8bf onesf = __builtin_bit_cast(v8bf, onesu);

  const v4f zf = {0.f, 0.f, 0.f, 0.f};
  v4f o2[4][2], sacc[4];
  #pragma unroll
  for (int m2 = 0; m2 < 4; ++m2){
    o2[m2][0] = zf; o2[m2][1] = zf; sacc[m2] = zf;
  }
  #pragma unroll
  for (int ksi = 0; ksi < 2; ++ksi)
    #pragma unroll
    for (int m2 = 0; m2 < 4; ++m2){
      o2[m2][0] = MFMA16(pa[m2][ksi], __builtin_bit_cast(v8bf, bvu[0][ksi]), o2[m2][0]);
      o2[m2][1] = MFMA16(pa[m2][ksi], __builtin_bit_cast(v8bf, bvu[1][ksi]), o2[m2][1]);
      sacc[m2]  = MFMA16(pa[m2][ksi], onesf, sacc[m2]);
    }

  float inv[4][4];
  #pragma unroll
  for (int m2 = 0; m2 < 4; ++m2)
    #pragma unroll
    for (int r = 0; r < 4; ++r)
      inv[m2][r] = 1.0f / __shfl(sacc[m2][r], lnn & 48, 64);

  #pragma unroll
  for (int m2 = 0; m2 < 4; ++m2){
    #pragma unroll
    for (int n2 = 0; n2 < 2; ++n2){
      #pragma unroll
      for (int r = 0; r < 4; ++r){
        int row = m2*16 + lg*4 + r;
        if (row < 49){
          float val = o2[m2][n2][r] * inv[m2][r];
          aout[(w * 49u + (u32)row) * 192u + (u32)(h*32 + n2*16 + lr)] = f2bf(val);
        }
      }
    }
  }
}

// ------------------------------ launcher -----------------------------------
extern "C" void kernel_launch(void* const* d_in, const int* in_sizes, int n_in,
                              void* d_out, int out_size, void* d_ws, size_t ws_size,
                              hipStream_t stream){
  const float* x     = (const float*)d_in[0];
  const float* n1g   = (const float*)d_in[1];
  const float* n1b   = (const float*)d_in[2];
  const float* qkvw  = (const float*)d_in[3];
  const float* qkvb  = (const float*)d_in[4];
  const float* rpb   = (const float*)d_in[5];
  const float* projw = (const float*)d_in[6];
  const float* projb = (const float*)d_in[7];
  const float* n2g   = (const float*)d_in[8];
  const float* n2b   = (const float*)d_in[9];
  const float* fc1w  = (const float*)d_in[10];
  const float* fc1b  = (const float*)d_in[11];
  const float* fc2w  = (const float*)d_in[12];
  const float* fc2b  = (const float*)d_in[13];
  float* out = (float*)d_out;

  char* ws  = (char*)d_ws;
  u16* bufA = (u16*)ws;                       // qkv 462MB -> h1 chunks
  u16* bufB = (u16*)(ws + 462422016L);        // xw -> attn_out -> xln2
  u16* wq   = (u16*)(ws + 616562688L);
  u16* wp   = wq + 110592;
  u16* w1   = wp + 36864;
  u16* w2   = w1 + 147456;
  float* bmt = (float*)d_out;   // 98304 floats, consumed by attn before proj

  convw<<<1728, 256, 0, stream>>>(qkvw, projw, fc1w, fc2w, wq);
  bmt_k<<<384, 256, 0, stream>>>(rpb, bmt);

  // LN1 + shift + window partition
  ln_kern<true><<<25088, 256, 0, stream>>>(x, n1g, n1b, bufB);
  // qkv (M=401408, N=576, K=192) -> permuted q,k,v.  grid = 3136*9 swizzled
  gemm_bt<0, 192, 192><<<3136*9, 512, 0, stream>>>(bufB, 0, wq, 192, 9,
                                                   qkvb, bufA, nullptr, nullptr, 0);
  // windowed attention
  attn_k<<<12288, 256, 0, stream>>>(bufA, bmt, bufB);
  // proj (N=192) + scatter + residual -> d_out (spatial order)
  gemm_bt<1, 192, 192><<<3136*3, 512, 0, stream>>>(bufB, 0, wp, 192, 3,
                                                   projb, nullptr, out, x, 0);
  // LN2 (spatial order, linear)
  ln_kern<false><<<25088, 256, 0, stream>>>(out, n2g, n2b, bufB);
  // MLP in 2 token-chunks (h1 chunk reuses bufA); all spatial-linear
  for (int c = 0; c < 2; ++c){
    int off = c * 200704;
    gemm_bt<2, 192, 192><<<1568*12, 512, 0, stream>>>(bufB, off, w1, 192, 12,
                                                      fc1b, bufA, nullptr, nullptr, 0);
    gemm_bt<3, 768, 768><<<1568*3, 512, 0, stream>>>(bufA, 0, w2, 768, 3,
                                                     fc2b, nullptr, out, nullptr, off);
  }
}

// Round 14
// 1374.014 us; speedup vs baseline: 1.6638x; 1.0426x over previous
//
#include <hip/hip_runtime.h>
#include <stdint.h>
#include <math.h>

// ---------------------------------------------------------------------------
// Swin block, MI355X. B=32 H=W=112 C=192 NH=6 hd=32 WS=7 SS=3 -> 8192 windows,
// 49 tokens, 401408 token-rows.
// R14: per-EPI epilogue orientation, chosen by measurement.
//   EPI 0 (qkv):   TRANSPOSED mfma(W,A) -> D[channel][token], packed 8B
//                  stores into the permuted q/k/v layout (R9: 267->253us).
//   EPI 1/2/3:     UNTRANSPOSED mfma(A,W) -> D[token][channel], lane-
//                  contiguous scalar/fp32 stores (R8: best for fp32 RMW +
//                  h1 stream; all-transposed cost ~65us across these).
// Everything else identical to R13 (XCD group swizzle, 512-thr 8-wave,
// separate LN passes, R8 attn).
// ---------------------------------------------------------------------------

typedef unsigned short u16;
typedef unsigned int   u32;
typedef __bf16 v8bf __attribute__((ext_vector_type(8)));
typedef float  v4f  __attribute__((ext_vector_type(4)));
typedef u16    v8u16 __attribute__((ext_vector_type(8)));
typedef u16    v4u16 __attribute__((ext_vector_type(4)));

#define MFMA16(a,b,c) __builtin_amdgcn_mfma_f32_16x16x32_bf16(a,b,c,0,0,0)

#define HSTR 77070336L          // elems per q/k/v array (8192*6*49*32)
#define QSC  0.17677669529663687f

__device__ __forceinline__ u16 f2bf(float f){
  return __builtin_bit_cast(u16, (__bf16)f);   // v_cvt RNE
}

__device__ __forceinline__ void async16(void* lds, const void* g){
  __builtin_amdgcn_global_load_lds(
      (__attribute__((address_space(1))) void*)(g),
      (__attribute__((address_space(3))) void*)(lds), 16, 0, 0);
}

// --------------------- combined weight convert (contiguous dst) ------------
// q-rows of qkv_w (first 192*192 elems) pre-scaled by hd^-0.5.
__global__ __launch_bounds__(256)
void convw(const float* __restrict__ s0, const float* __restrict__ s1,
           const float* __restrict__ s2, const float* __restrict__ s3,
           u16* __restrict__ d){
  int i = blockIdx.x * 256 + threadIdx.x;        // < 442368
  float v;
  if (i < 110592){
    v = s0[i];
    if (i < 36864) v *= QSC;
  }
  else if (i < 147456)  v = s1[i - 110592];
  else if (i < 294912)  v = s2[i - 147456];
  else                  v = s3[i - 294912];
  d[i] = f2bf(v);
}

// -------------------- fused rel-pos-bias + shift-mask table ----------------
// layout: [cls][h][m][n][lr][lg*4+r]  (matches MFMA C fragment, b128/lane)
__global__ __launch_bounds__(256)
void bmt_k(const float* __restrict__ rpb, float* __restrict__ bmt){
  int idx = blockIdx.x * 256 + threadIdx.x;      // 98304 total
  int r  = idx & 3, lg = (idx >> 2) & 3, lr = (idx >> 4) & 15;
  int n  = (idx >> 8) & 3, m = (idx >> 10) & 3;
  int t  = idx >> 12; int h = t % 6, cls = t / 6;
  int row = m*16 + lg*4 + r, col = n*16 + lr;
  float v;
  if (row >= 49 || col >= 49){
    v = -1e30f;
  } else {
    int i1 = row / 7, j1 = row - i1 * 7;
    int i2 = col / 7, j2 = col - i2 * 7;
    int ridx = (i1 - i2 + 6) * 13 + (j1 - j2 + 6);
    v = rpb[ridx * 6 + h];
    int lh1 = (cls & 2) ? (i1 < 4 ? 1 : 2) : 0;
    int lw1 = (cls & 1) ? (j1 < 4 ? 1 : 2) : 0;
    int lh2 = (cls & 2) ? (i2 < 4 ? 1 : 2) : 0;
    int lw2 = (cls & 1) ? (j2 < 4 ? 1 : 2) : 0;
    if (lh1 * 3 + lw1 != lh2 * 3 + lw2) v -= 100.f;
  }
  bmt[idx] = v;
}

// ----------------------- LayerNorm (optionally gathered) -------------------
// 16 lanes per token, 4 tokens per wave; lane handles 12 channels (3 float4).
template<bool GATHER>
__global__ __launch_bounds__(256)
void ln_kern(const float* __restrict__ x, const float* __restrict__ g,
             const float* __restrict__ b, u16* __restrict__ o){
  const int ts  = threadIdx.x >> 4;
  const int l16 = threadIdx.x & 15;
  const int r   = blockIdx.x * 16 + ts;          // < 401408
  const float* src;
  if (GATHER){
    u32 wdx = (u32)r / 49u; int nn = r - (int)wdx * 49;
    int bb = (int)(wdx >> 8); int wl = (int)(wdx & 255);
    int wh = wl >> 4, wwi = wl & 15;
    int ii = (int)((u32)nn / 7u), jj = nn - ii * 7;
    int th = wh * 7 + ii + 3;  if (th >= 112) th -= 112;
    int tw = wwi * 7 + jj + 3; if (tw >= 112) tw -= 112;
    src = x + (u32)(bb * 12544 + th * 112 + tw) * 192u;
  } else {
    src = x + (u32)r * 192u;
  }
  const float4 a0 = *(const float4*)(src + l16*12);
  const float4 a1 = *(const float4*)(src + l16*12 + 4);
  const float4 a2 = *(const float4*)(src + l16*12 + 8);
  float sm = ((a0.x+a0.y)+(a0.z+a0.w)) + ((a1.x+a1.y)+(a1.z+a1.w))
           + ((a2.x+a2.y)+(a2.z+a2.w));
  float sq = ((a0.x*a0.x+a0.y*a0.y)+(a0.z*a0.z+a0.w*a0.w))
           + ((a1.x*a1.x+a1.y*a1.y)+(a1.z*a1.z+a1.w*a1.w))
           + ((a2.x*a2.x+a2.y*a2.y)+(a2.z*a2.z+a2.w*a2.w));
  #pragma unroll
  for (int d = 1; d < 16; d <<= 1){
    sm += __shfl_xor(sm, d, 64);
    sq += __shfl_xor(sq, d, 64);
  }
  float mean = sm * (1.f/192.f);
  float var  = sq * (1.f/192.f) - mean * mean;
  float rs   = rsqrtf(var + 1e-5f);
  const float4 g0 = *(const float4*)(g + l16*12);
  const float4 g1 = *(const float4*)(g + l16*12 + 4);
  const float4 g2 = *(const float4*)(g + l16*12 + 8);
  const float4 b0 = *(const float4*)(b + l16*12);
  const float4 b1 = *(const float4*)(b + l16*12 + 4);
  const float4 b2 = *(const float4*)(b + l16*12 + 8);
  u16* dst = o + (u32)r * 192u + l16 * 12;
  v4u16 w0, w1, w2;
  w0[0]=f2bf((a0.x-mean)*rs*g0.x+b0.x); w0[1]=f2bf((a0.y-mean)*rs*g0.y+b0.y);
  w0[2]=f2bf((a0.z-mean)*rs*g0.z+b0.z); w0[3]=f2bf((a0.w-mean)*rs*g0.w+b0.w);
  w1[0]=f2bf((a1.x-mean)*rs*g1.x+b1.x); w1[1]=f2bf((a1.y-mean)*rs*g1.y+b1.y);
  w1[2]=f2bf((a1.z-mean)*rs*g1.z+b1.z); w1[3]=f2bf((a1.w-mean)*rs*g1.w+b1.w);
  w2[0]=f2bf((a2.x-mean)*rs*g2.x+b2.x); w2[1]=f2bf((a2.y-mean)*rs*g2.y+b2.y);
  w2[2]=f2bf((a2.z-mean)*rs*g2.z+b2.z); w2[3]=f2bf((a2.w-mean)*rs*g2.w+b2.w);
  *(v4u16*)(dst)     = w0;
  *(v4u16*)(dst + 4) = w1;
  *(v4u16*)(dst + 8) = w2;
}

// ------------------------------- GEMM (A @ W^T) ----------------------------
// BM=128, BN=64, BK=192/stage, 512 threads = 8 waves, wave = 32x32 quadrant.
// 1D grid, XCD-aligned group swizzle (56 row-blocks x ncol, col-major).
// TRN = (EPI==0): acc[n][m] = mfma(wf, af) -> D[channel][token], packed 8B
// stores. Else: acc[m][n] = mfma(af, wf) -> D[token][channel], lane-
// contiguous stores (best for fp32 RMW epilogues and the h1 stream).
template<int EPI, int LDA, int LDW>
__global__ __launch_bounds__(512)
void gemm_bt(const u16* __restrict__ A, int aRowOff,
             const u16* __restrict__ W, int K, int ncol,
             const float* __restrict__ bias,
             u16* __restrict__ ob, float* __restrict__ of,
             const float* __restrict__ xres, int oRowOff){
  constexpr bool TRN = (EPI == 0);
  __shared__ __align__(16) u16 sA[128 * 200];
  __shared__ __align__(16) u16 sW[64 * 200];
  const int tid = threadIdx.x;
  const int wv = tid >> 6, lnn = tid & 63;
  const int lr = lnn & 15, lg = lnn >> 4;
  // group swizzle
  const int win = 56 * ncol;
  const int grp = (int)blockIdx.x / win, loc = (int)blockIdx.x - grp * win;
  const int rloc = loc % 56, cblk = loc / 56;
  const int m0   = (grp * 56 + rloc) * 128;
  const int col0 = cblk * 64;
  const int wr = wv >> 1, wc = wv & 1;

  const int c0   = col0 + wc*32 + lr;        // untransposed: channel per lane
  const int chb0 = col0 + wc*32 + lg*4;      // transposed: 4-channel base
  const int chb1 = chb0 + 16;

  v4f acc[2][2];     // TRN: [n][m] channel-major; else [m][n] token-major
  if (TRN){
    float4 bv0 = *(const float4*)&bias[chb0];
    float4 bv1 = *(const float4*)&bias[chb1];
    if (chb0 < 192){ bv0.x*=QSC; bv0.y*=QSC; bv0.z*=QSC; bv0.w*=QSC; }
    if (chb1 < 192){ bv1.x*=QSC; bv1.y*=QSC; bv1.z*=QSC; bv1.w*=QSC; }
    acc[0][0] = acc[0][1] = (v4f){bv0.x, bv0.y, bv0.z, bv0.w};
    acc[1][0] = acc[1][1] = (v4f){bv1.x, bv1.y, bv1.z, bv1.w};
  } else {
    const float b0v = bias[c0];
    const float b1v = bias[c0 + 16];
    #pragma unroll
    for (int m = 0; m < 2; ++m){
      acc[m][0] = (v4f){b0v, b0v, b0v, b0v};
      acc[m][1] = (v4f){b1v, b1v, b1v, b1v};
    }
  }

  const int rA0 = (int)((u32)tid / 25u);
  const int cA0 = tid - rA0 * 25;
  const u32 aBase = (u32)(aRowOff + m0);
  const int nK = K / 192;
  for (int ks = 0; ks < nK; ++ks){
    if (ks) __syncthreads();
    const int k0 = ks * 192;
    // A tile: 128 rows x 25 chunks(16B) = 3200; 6 iters + 128-tail
    int ra = rA0, ca = cA0;
    #pragma unroll
    for (int it = 0; it < 6; ++it){
      int cc = (ca == 24) ? 23 : ca;
      async16((char*)sA + (size_t)(it * 512 + wv * 64) * 16,
              A + (aBase + (u32)ra) * (u32)LDA + (u32)(k0 + cc * 8));
      ra += 20; ca += 12; if (ca >= 25){ ca -= 25; ra += 1; }
    }
    if (tid < 128){
      int cc = (ca == 24) ? 23 : ca;
      async16((char*)sA + (size_t)(3072 + wv * 64) * 16,
              A + (aBase + (u32)ra) * (u32)LDA + (u32)(k0 + cc * 8));
    }
    // W tile: 64 rows x 25 chunks = 1600; 3 iters + 64-tail
    int rw = rA0, cw = cA0;
    #pragma unroll
    for (int it = 0; it < 3; ++it){
      int cc = (cw == 24) ? 23 : cw;
      async16((char*)sW + (size_t)(it * 512 + wv * 64) * 16,
              W + (u32)(col0 + rw) * (u32)LDW + (u32)(k0 + cc * 8));
      rw += 20; cw += 12; if (cw >= 25){ cw -= 25; rw += 1; }
    }
    if (tid < 64){
      int cc = (cw == 24) ? 23 : cw;
      async16((char*)sW + (size_t)1536 * 16,
              W + (u32)(col0 + rw) * (u32)LDW + (u32)(k0 + cc * 8));
    }
    __syncthreads();   // drains vmcnt(0) -> staged data visible

    #pragma unroll
    for (int kk = 0; kk < 6; ++kk){
      v8bf af[2], wf[2];
      #pragma unroll
      for (int m = 0; m < 2; ++m)
        af[m] = *(const v8bf*)&sA[(wr*32 + m*16 + lr) * 200 + kk*32 + lg*8];
      #pragma unroll
      for (int n = 0; n < 2; ++n)
        wf[n] = *(const v8bf*)&sW[(wc*32 + n*16 + lr) * 200 + kk*32 + lg*8];
      if (TRN){
        #pragma unroll
        for (int n = 0; n < 2; ++n)
          #pragma unroll
          for (int m = 0; m < 2; ++m)
            acc[n][m] = MFMA16(wf[n], af[m], acc[n][m]);
      } else {
        #pragma unroll
        for (int m = 0; m < 2; ++m)
          #pragma unroll
          for (int n = 0; n < 2; ++n)
            acc[m][n] = MFMA16(af[m], wf[n], acc[m][n]);
      }
    }
  }

  // ------------------------------ epilogues --------------------------------
  if (EPI == 0){
    // TRN: D row = channel (4*lg+r), D col = token (lr); packed 8B stores.
    // addr = which*HSTR + wdx*9408 + hh*1568 + nn*32 + dd   (ob bf16)
    u32 chpart[2];
    const int chbs[2] = {chb0, chb1};
    #pragma unroll
    for (int n = 0; n < 2; ++n){
      int ch = chbs[n];
      int which = (ch >= 384) ? 2 : ((ch >= 192) ? 1 : 0);
      int rem = ch - which * 192;
      chpart[n] = (u32)which * 77070336u + (u32)((rem >> 5) * 1568 + (rem & 31));
    }
    #pragma unroll
    for (int m = 0; m < 2; ++m){
      const int t = m0 + wr*32 + m*16 + lr;
      u32 wdx = (u32)t / 49u; u32 tnn = (u32)t - wdx * 49u;
      const u32 rowpart = wdx * 9408u + tnn * 32u;
      #pragma unroll
      for (int n = 0; n < 2; ++n){
        v4u16 pk;
        pk[0] = f2bf(acc[n][m][0]); pk[1] = f2bf(acc[n][m][1]);
        pk[2] = f2bf(acc[n][m][2]); pk[3] = f2bf(acc[n][m][3]);
        *(v4u16*)&ob[chpart[n] + rowpart] = pk;
      }
    }
  } else if (EPI == 1){
    // untransposed: row = token (4*lg+r), col = channel (lr); lane-contiguous
    #pragma unroll
    for (int m = 0; m < 2; ++m){
      #pragma unroll
      for (int r = 0; r < 4; ++r){
        const int gr = m0 + wr*32 + m*16 + lg*4 + r;
        u32 wdx = (u32)gr / 49u; int nn = gr - (int)wdx * 49;
        int bb = (int)(wdx >> 8); int wl = (int)(wdx & 255);
        int wh = wl >> 4, wwi = wl & 15;
        int ii = (int)((u32)nn / 7u), jj = nn - ii * 7;
        int th = wh * 7 + ii + 3;  if (th >= 112) th -= 112;
        int tw = wwi * 7 + jj + 3; if (tw >= 112) tw -= 112;
        u32 adr = (u32)(bb * 12544 + th * 112 + tw) * 192u + (u32)c0;
        of[adr]      = xres[adr]      + acc[m][0][r];
        of[adr + 16] = xres[adr + 16] + acc[m][1][r];
      }
    }
  } else if (EPI == 3){
    // rows already spatial -> linear += (lane-contiguous fp32)
    #pragma unroll
    for (int m = 0; m < 2; ++m){
      #pragma unroll
      for (int r = 0; r < 4; ++r){
        const u32 adr = (u32)(oRowOff + m0 + wr*32 + m*16 + lg*4 + r) * 192u
                        + (u32)c0;
        of[adr]      += acc[m][0][r];
        of[adr + 16] += acc[m][1][r];
      }
    }
  } else {  // EPI == 2: gelu -> h1 bf16, row-linear, lane-contiguous
    #pragma unroll
    for (int m = 0; m < 2; ++m){
      #pragma unroll
      for (int r = 0; r < 4; ++r){
        const u32 base = (u32)(m0 + wr*32 + m*16 + lg*4 + r) * 768u + (u32)c0;
        float v0 = acc[m][0][r], v1 = acc[m][1][r];
        ob[base]      = f2bf(0.5f * v0 * (1.0f + erff(v0 * 0.7071067811865475f)));
        ob[base + 16] = f2bf(0.5f * v1 * (1.0f + erff(v1 * 0.7071067811865475f)));
      }
    }
  }
}

// ------------------------------- attention (R8 version) --------------------
// one wave per (window, head); 4 waves / block.  49 padded to 64.
// Scores bounded -> no max pass; masked (-100) / pad (-1e30) underflow to 0.
__global__ __launch_bounds__(256, 4)
void attn_k(const u16* __restrict__ qkv, const float* __restrict__ bmt,
            u16* __restrict__ aout){
  __shared__ __align__(16) u16 plds[4][64 * 64];   // 32 KB total
  const int wv = threadIdx.x >> 6, lnn = threadIdx.x & 63;
  const int lr = lnn & 15, lg = lnn >> 4;
  const u32 gid = (u32)blockIdx.x * 4u + (u32)wv;   // < 49152
  const u32 w = gid / 6u; const int h = (int)(gid - w * 6u);
  const u16* qb = qkv + (size_t)gid * 1568;
  const u16* kb = qb + HSTR;
  const u16* vb = kb + HSTR;

  // C-init = bias+mask table (b128 per lane, L2/L3-resident)
  const int wl = (int)(w & 255);
  const int cls = (((wl >> 4) == 15) ? 2 : 0) | (((wl & 15) == 15) ? 1 : 0);
  const float* bmv = bmt + ((u32)(cls * 6 + h) << 12);
  v4f s[4][4];
  #pragma unroll
  for (int m = 0; m < 4; ++m)
    #pragma unroll
    for (int n = 0; n < 4; ++n)
      s[m][n] = *(const v4f*)&bmv[(u32)(((m*4 + n)*16 + lr)*16 + lg*4)];

  // Q.K^T on top of bias
  v8bf aq[4], bk4[4];
  #pragma unroll
  for (int m = 0; m < 4; ++m) aq[m]  = *(const v8bf*)(qb + (m*16 + lr)*32 + lg*8);
  #pragma unroll
  for (int n = 0; n < 4; ++n) bk4[n] = *(const v8bf*)(kb + (n*16 + lr)*32 + lg*8);
  #pragma unroll
  for (int m = 0; m < 4; ++m)
    #pragma unroll
    for (int n = 0; n < 4; ++n) s[m][n] = MFMA16(aq[m], bk4[n], s[m][n]);

  // V fragments from global, k-permuted (pads multiply P==0 -> harmless)
  v8u16 bvu[2][2];
  #pragma unroll
  for (int n2 = 0; n2 < 2; ++n2)
    #pragma unroll
    for (int ksi = 0; ksi < 2; ++ksi)
      #pragma unroll
      for (int e = 0; e < 8; ++e){
        int kp = ksi * 32 + lg * 8 + e;
        int t  = (kp >> 2) + (kp & 3) * 16;
        bvu[n2][ksi][e] = vb[(u32)(t * 32 + n2 * 16 + lr)];
      }

  // P = exp(s), packed store (pos = lr*4+n), XOR-swizzled rows
  #pragma unroll
  for (int m = 0; m < 4; ++m)
    #pragma unroll
    for (int r = 0; r < 4; ++r){
      int row = m*16 + lg*4 + r;
      v4u16 pk;
      pk[0] = f2bf(__expf(s[m][0][r]));
      pk[1] = f2bf(__expf(s[m][1][r]));
      pk[2] = f2bf(__expf(s[m][2][r]));
      pk[3] = f2bf(__expf(s[m][3][r]));
      *(v4u16*)((char*)&plds[wv][0] + row*128 + ((lr*8) ^ ((row & 7) << 4))) = pk;
    }

  v8bf pa[4][2];
  #pragma unroll
  for (int m2 = 0; m2 < 4; ++m2)
    #pragma unroll
    for (int ksi = 0; ksi < 2; ++ksi){
      int row2 = m2*16 + lr;
      pa[m2][ksi] = *(const v8bf*)((const char*)&plds[wv][0] + row2*128 +
                                   ((ksi*64 + lg*16) ^ ((row2 & 7) << 4)));
    }

  // ones B-frag (col 0 only) for row-sums
  v8u16 onesu;
  #pragma unroll
  for (int e = 0; e < 8; ++e) onesu[e] = (lr == 0) ? (u16)0x3F80 : (u16)0;
  const v8bf onesf = __builtin_bit_cast(v8bf, onesu);

  const v4f zf = {0.f, 0.f, 0.f, 0.f};
  v4f o2[4][2], sacc[4];
  #pragma unroll
  for (int m2 = 0; m2 < 4; ++m2){
    o2[m2][0] = zf; o2[m2][1] = zf; sacc[m2] = zf;
  }
  #pragma unroll
  for (int ksi = 0; ksi < 2; ++ksi)
    #pragma unroll
    for (int m2 = 0; m2 < 4; ++m2){
      o2[m2][0] = MFMA16(pa[m2][ksi], __builtin_bit_cast(v8bf, bvu[0][ksi]), o2[m2][0]);
      o2[m2][1] = MFMA16(pa[m2][ksi], __builtin_bit_cast(v8bf, bvu[1][ksi]), o2[m2][1]);
      sacc[m2]  = MFMA16(pa[m2][ksi], onesf, sacc[m2]);
    }

  float inv[4][4];
  #pragma unroll
  for (int m2 = 0; m2 < 4; ++m2)
    #pragma unroll
    for (int r = 0; r < 4; ++r)
      inv[m2][r] = 1.0f / __shfl(sacc[m2][r], lnn & 48, 64);

  #pragma unroll
  for (int m2 = 0; m2 < 4; ++m2){
    #pragma unroll
    for (int n2 = 0; n2 < 2; ++n2){
      #pragma unroll
      for (int r = 0; r < 4; ++r){
        int row = m2*16 + lg*4 + r;
        if (row < 49){
          float val = o2[m2][n2][r] * inv[m2][r];
          aout[(w * 49u + (u32)row) * 192u + (u32)(h*32 + n2*16 + lr)] = f2bf(val);
        }
      }
    }
  }
}

// ------------------------------ launcher -----------------------------------
extern "C" void kernel_launch(void* const* d_in, const int* in_sizes, int n_in,
                              void* d_out, int out_size, void* d_ws, size_t ws_size,
                              hipStream_t stream){
  const float* x     = (const float*)d_in[0];
  const float* n1g   = (const float*)d_in[1];
  const float* n1b   = (const float*)d_in[2];
  const float* qkvw  = (const float*)d_in[3];
  const float* qkvb  = (const float*)d_in[4];
  const float* rpb   = (const float*)d_in[5];
  const float* projw = (const float*)d_in[6];
  const float* projb = (const float*)d_in[7];
  const float* n2g   = (const float*)d_in[8];
  const float* n2b   = (const float*)d_in[9];
  const float* fc1w  = (const float*)d_in[10];
  const float* fc1b  = (const float*)d_in[11];
  const float* fc2w  = (const float*)d_in[12];
  const float* fc2b  = (const float*)d_in[13];
  float* out = (float*)d_out;

  char* ws  = (char*)d_ws;
  u16* bufA = (u16*)ws;                       // qkv 462MB -> h1 chunks
  u16* bufB = (u16*)(ws + 462422016L);        // xw -> attn_out -> xln2
  u16* wq   = (u16*)(ws + 616562688L);
  u16* wp   = wq + 110592;
  u16* w1   = wp + 36864;
  u16* w2   = w1 + 147456;
  float* bmt = (float*)d_out;   // 98304 floats, consumed by attn before proj

  convw<<<1728, 256, 0, stream>>>(qkvw, projw, fc1w, fc2w, wq);
  bmt_k<<<384, 256, 0, stream>>>(rpb, bmt);

  // LN1 + shift + window partition
  ln_kern<true><<<25088, 256, 0, stream>>>(x, n1g, n1b, bufB);
  // qkv (M=401408, N=576, K=192) -> permuted q,k,v.  grid = 3136*9 swizzled
  gemm_bt<0, 192, 192><<<3136*9, 512, 0, stream>>>(bufB, 0, wq, 192, 9,
                                                   qkvb, bufA, nullptr, nullptr, 0);
  // windowed attention
  attn_k<<<12288, 256, 0, stream>>>(bufA, bmt, bufB);
  // proj (N=192) + scatter + residual -> d_out (spatial order)
  gemm_bt<1, 192, 192><<<3136*3, 512, 0, stream>>>(bufB, 0, wp, 192, 3,
                                                   projb, nullptr, out, x, 0);
  // LN2 (spatial order, linear)
  ln_kern<false><<<25088, 256, 0, stream>>>(out, n2g, n2b, bufB);
  // MLP in 2 token-chunks (h1 chunk reuses bufA); all spatial-linear
  for (int c = 0; c < 2; ++c){
    int off = c * 200704;
    gemm_bt<2, 192, 192><<<1568*12, 512, 0, stream>>>(bufB, off, w1, 192, 12,
                                                      fc1b, bufA, nullptr, nullptr, 0);
    gemm_bt<3, 768, 768><<<1568*3, 512, 0, stream>>>(bufA, 0, w2, 768, 3,
                                                     fc2b, nullptr, out, nullptr, off);
  }
}

// Round 15
// 1348.804 us; speedup vs baseline: 1.6949x; 1.0187x over previous
//
#include <hip/hip_runtime.h>
#include <stdint.h>
#include <math.h>

// ---------------------------------------------------------------------------
// Swin block, MI355X. B=32 H=W=112 C=192 NH=6 hd=32 WS=7 SS=3 -> 8192 windows,
// 49 tokens, 401408 token-rows.
// R15 = R14 compute kernels (frozen) + L3 cache-blocking across kernels:
//   qkv+attn run in 8 chunks of 1024 windows, qkv scratch (58MB) reused at
//   the same addresses each chunk -> dirty lines overwritten in-L3, attn
//   reads are L3-hits;
//   fc1+fc2 run in 8 chunks of 50176 tokens, h1 (77MB) likewise L3-blocked.
// Pure orchestration: gemm_bt gains `hstr`, attn_k gains `wOff`/`hstr`.
// ---------------------------------------------------------------------------

typedef unsigned short u16;
typedef unsigned int   u32;
typedef __bf16 v8bf __attribute__((ext_vector_type(8)));
typedef float  v4f  __attribute__((ext_vector_type(4)));
typedef u16    v8u16 __attribute__((ext_vector_type(8)));
typedef u16    v4u16 __attribute__((ext_vector_type(4)));

#define MFMA16(a,b,c) __builtin_amdgcn_mfma_f32_16x16x32_bf16(a,b,c,0,0,0)

#define QSC  0.17677669529663687f

__device__ __forceinline__ u16 f2bf(float f){
  return __builtin_bit_cast(u16, (__bf16)f);   // v_cvt RNE
}

__device__ __forceinline__ void async16(void* lds, const void* g){
  __builtin_amdgcn_global_load_lds(
      (__attribute__((address_space(1))) void*)(g),
      (__attribute__((address_space(3))) void*)(lds), 16, 0, 0);
}

// --------------------- combined weight convert (contiguous dst) ------------
// q-rows of qkv_w (first 192*192 elems) pre-scaled by hd^-0.5.
__global__ __launch_bounds__(256)
void convw(const float* __restrict__ s0, const float* __restrict__ s1,
           const float* __restrict__ s2, const float* __restrict__ s3,
           u16* __restrict__ d){
  int i = blockIdx.x * 256 + threadIdx.x;        // < 442368
  float v;
  if (i < 110592){
    v = s0[i];
    if (i < 36864) v *= QSC;
  }
  else if (i < 147456)  v = s1[i - 110592];
  else if (i < 294912)  v = s2[i - 147456];
  else                  v = s3[i - 294912];
  d[i] = f2bf(v);
}

// -------------------- fused rel-pos-bias + shift-mask table ----------------
// layout: [cls][h][m][n][lr][lg*4+r]  (matches MFMA C fragment, b128/lane)
__global__ __launch_bounds__(256)
void bmt_k(const float* __restrict__ rpb, float* __restrict__ bmt){
  int idx = blockIdx.x * 256 + threadIdx.x;      // 98304 total
  int r  = idx & 3, lg = (idx >> 2) & 3, lr = (idx >> 4) & 15;
  int n  = (idx >> 8) & 3, m = (idx >> 10) & 3;
  int t  = idx >> 12; int h = t % 6, cls = t / 6;
  int row = m*16 + lg*4 + r, col = n*16 + lr;
  float v;
  if (row >= 49 || col >= 49){
    v = -1e30f;
  } else {
    int i1 = row / 7, j1 = row - i1 * 7;
    int i2 = col / 7, j2 = col - i2 * 7;
    int ridx = (i1 - i2 + 6) * 13 + (j1 - j2 + 6);
    v = rpb[ridx * 6 + h];
    int lh1 = (cls & 2) ? (i1 < 4 ? 1 : 2) : 0;
    int lw1 = (cls & 1) ? (j1 < 4 ? 1 : 2) : 0;
    int lh2 = (cls & 2) ? (i2 < 4 ? 1 : 2) : 0;
    int lw2 = (cls & 1) ? (j2 < 4 ? 1 : 2) : 0;
    if (lh1 * 3 + lw1 != lh2 * 3 + lw2) v -= 100.f;
  }
  bmt[idx] = v;
}

// ----------------------- LayerNorm (optionally gathered) -------------------
// 16 lanes per token, 4 tokens per wave; lane handles 12 channels (3 float4).
template<bool GATHER>
__global__ __launch_bounds__(256)
void ln_kern(const float* __restrict__ x, const float* __restrict__ g,
             const float* __restrict__ b, u16* __restrict__ o){
  const int ts  = threadIdx.x >> 4;
  const int l16 = threadIdx.x & 15;
  const int r   = blockIdx.x * 16 + ts;          // < 401408
  const float* src;
  if (GATHER){
    u32 wdx = (u32)r / 49u; int nn = r - (int)wdx * 49;
    int bb = (int)(wdx >> 8); int wl = (int)(wdx & 255);
    int wh = wl >> 4, wwi = wl & 15;
    int ii = (int)((u32)nn / 7u), jj = nn - ii * 7;
    int th = wh * 7 + ii + 3;  if (th >= 112) th -= 112;
    int tw = wwi * 7 + jj + 3; if (tw >= 112) tw -= 112;
    src = x + (u32)(bb * 12544 + th * 112 + tw) * 192u;
  } else {
    src = x + (u32)r * 192u;
  }
  const float4 a0 = *(const float4*)(src + l16*12);
  const float4 a1 = *(const float4*)(src + l16*12 + 4);
  const float4 a2 = *(const float4*)(src + l16*12 + 8);
  float sm = ((a0.x+a0.y)+(a0.z+a0.w)) + ((a1.x+a1.y)+(a1.z+a1.w))
           + ((a2.x+a2.y)+(a2.z+a2.w));
  float sq = ((a0.x*a0.x+a0.y*a0.y)+(a0.z*a0.z+a0.w*a0.w))
           + ((a1.x*a1.x+a1.y*a1.y)+(a1.z*a1.z+a1.w*a1.w))
           + ((a2.x*a2.x+a2.y*a2.y)+(a2.z*a2.z+a2.w*a2.w));
  #pragma unroll
  for (int d = 1; d < 16; d <<= 1){
    sm += __shfl_xor(sm, d, 64);
    sq += __shfl_xor(sq, d, 64);
  }
  float mean = sm * (1.f/192.f);
  float var  = sq * (1.f/192.f) - mean * mean;
  float rs   = rsqrtf(var + 1e-5f);
  const float4 g0 = *(const float4*)(g + l16*12);
  const float4 g1 = *(const float4*)(g + l16*12 + 4);
  const float4 g2 = *(const float4*)(g + l16*12 + 8);
  const float4 b0 = *(const float4*)(b + l16*12);
  const float4 b1 = *(const float4*)(b + l16*12 + 4);
  const float4 b2 = *(const float4*)(b + l16*12 + 8);
  u16* dst = o + (u32)r * 192u + l16 * 12;
  v4u16 w0, w1, w2;
  w0[0]=f2bf((a0.x-mean)*rs*g0.x+b0.x); w0[1]=f2bf((a0.y-mean)*rs*g0.y+b0.y);
  w0[2]=f2bf((a0.z-mean)*rs*g0.z+b0.z); w0[3]=f2bf((a0.w-mean)*rs*g0.w+b0.w);
  w1[0]=f2bf((a1.x-mean)*rs*g1.x+b1.x); w1[1]=f2bf((a1.y-mean)*rs*g1.y+b1.y);
  w1[2]=f2bf((a1.z-mean)*rs*g1.z+b1.z); w1[3]=f2bf((a1.w-mean)*rs*g1.w+b1.w);
  w2[0]=f2bf((a2.x-mean)*rs*g2.x+b2.x); w2[1]=f2bf((a2.y-mean)*rs*g2.y+b2.y);
  w2[2]=f2bf((a2.z-mean)*rs*g2.z+b2.z); w2[3]=f2bf((a2.w-mean)*rs*g2.w+b2.w);
  *(v4u16*)(dst)     = w0;
  *(v4u16*)(dst + 4) = w1;
  *(v4u16*)(dst + 8) = w2;
}

// ------------------------------- GEMM (A @ W^T) ----------------------------
// BM=128, BN=64, BK=192/stage, 512 threads = 8 waves, wave = 32x32 quadrant.
// 1D grid, XCD-aligned group swizzle (56 row-blocks x ncol, col-major).
// TRN = (EPI==0): acc[n][m] = mfma(wf, af) -> D[channel][token], packed 8B
// stores (chunk-local qkv buffer, stride hstr). Else: acc[m][n] =
// mfma(af, wf) -> D[token][channel], lane-contiguous stores.
template<int EPI, int LDA, int LDW>
__global__ __launch_bounds__(512)
void gemm_bt(const u16* __restrict__ A, int aRowOff,
             const u16* __restrict__ W, int K, int ncol,
             const float* __restrict__ bias,
             u16* __restrict__ ob, float* __restrict__ of,
             const float* __restrict__ xres, int oRowOff, u32 hstr){
  constexpr bool TRN = (EPI == 0);
  __shared__ __align__(16) u16 sA[128 * 200];
  __shared__ __align__(16) u16 sW[64 * 200];
  const int tid = threadIdx.x;
  const int wv = tid >> 6, lnn = tid & 63;
  const int lr = lnn & 15, lg = lnn >> 4;
  // group swizzle
  const int win = 56 * ncol;
  const int grp = (int)blockIdx.x / win, loc = (int)blockIdx.x - grp * win;
  const int rloc = loc % 56, cblk = loc / 56;
  const int m0   = (grp * 56 + rloc) * 128;
  const int col0 = cblk * 64;
  const int wr = wv >> 1, wc = wv & 1;

  const int c0   = col0 + wc*32 + lr;        // untransposed: channel per lane
  const int chb0 = col0 + wc*32 + lg*4;      // transposed: 4-channel base
  const int chb1 = chb0 + 16;

  v4f acc[2][2];     // TRN: [n][m] channel-major; else [m][n] token-major
  if (TRN){
    float4 bv0 = *(const float4*)&bias[chb0];
    float4 bv1 = *(const float4*)&bias[chb1];
    if (chb0 < 192){ bv0.x*=QSC; bv0.y*=QSC; bv0.z*=QSC; bv0.w*=QSC; }
    if (chb1 < 192){ bv1.x*=QSC; bv1.y*=QSC; bv1.z*=QSC; bv1.w*=QSC; }
    acc[0][0] = acc[0][1] = (v4f){bv0.x, bv0.y, bv0.z, bv0.w};
    acc[1][0] = acc[1][1] = (v4f){bv1.x, bv1.y, bv1.z, bv1.w};
  } else {
    const float b0v = bias[c0];
    const float b1v = bias[c0 + 16];
    #pragma unroll
    for (int m = 0; m < 2; ++m){
      acc[m][0] = (v4f){b0v, b0v, b0v, b0v};
      acc[m][1] = (v4f){b1v, b1v, b1v, b1v};
    }
  }

  const int rA0 = (int)((u32)tid / 25u);
  const int cA0 = tid - rA0 * 25;
  const u32 aBase = (u32)(aRowOff + m0);
  const int nK = K / 192;
  for (int ks = 0; ks < nK; ++ks){
    if (ks) __syncthreads();
    const int k0 = ks * 192;
    // A tile: 128 rows x 25 chunks(16B) = 3200; 6 iters + 128-tail
    int ra = rA0, ca = cA0;
    #pragma unroll
    for (int it = 0; it < 6; ++it){
      int cc = (ca == 24) ? 23 : ca;
      async16((char*)sA + (size_t)(it * 512 + wv * 64) * 16,
              A + (aBase + (u32)ra) * (u32)LDA + (u32)(k0 + cc * 8));
      ra += 20; ca += 12; if (ca >= 25){ ca -= 25; ra += 1; }
    }
    if (tid < 128){
      int cc = (ca == 24) ? 23 : ca;
      async16((char*)sA + (size_t)(3072 + wv * 64) * 16,
              A + (aBase + (u32)ra) * (u32)LDA + (u32)(k0 + cc * 8));
    }
    // W tile: 64 rows x 25 chunks = 1600; 3 iters + 64-tail
    int rw = rA0, cw = cA0;
    #pragma unroll
    for (int it = 0; it < 3; ++it){
      int cc = (cw == 24) ? 23 : cw;
      async16((char*)sW + (size_t)(it * 512 + wv * 64) * 16,
              W + (u32)(col0 + rw) * (u32)LDW + (u32)(k0 + cc * 8));
      rw += 20; cw += 12; if (cw >= 25){ cw -= 25; rw += 1; }
    }
    if (tid < 64){
      int cc = (cw == 24) ? 23 : cw;
      async16((char*)sW + (size_t)1536 * 16,
              W + (u32)(col0 + rw) * (u32)LDW + (u32)(k0 + cc * 8));
    }
    __syncthreads();   // drains vmcnt(0) -> staged data visible

    #pragma unroll
    for (int kk = 0; kk < 6; ++kk){
      v8bf af[2], wf[2];
      #pragma unroll
      for (int m = 0; m < 2; ++m)
        af[m] = *(const v8bf*)&sA[(wr*32 + m*16 + lr) * 200 + kk*32 + lg*8];
      #pragma unroll
      for (int n = 0; n < 2; ++n)
        wf[n] = *(const v8bf*)&sW[(wc*32 + n*16 + lr) * 200 + kk*32 + lg*8];
      if (TRN){
        #pragma unroll
        for (int n = 0; n < 2; ++n)
          #pragma unroll
          for (int m = 0; m < 2; ++m)
            acc[n][m] = MFMA16(wf[n], af[m], acc[n][m]);
      } else {
        #pragma unroll
        for (int m = 0; m < 2; ++m)
          #pragma unroll
          for (int n = 0; n < 2; ++n)
            acc[m][n] = MFMA16(af[m], wf[n], acc[m][n]);
      }
    }
  }

  // ------------------------------ epilogues --------------------------------
  if (EPI == 0){
    // TRN: D row = channel (4*lg+r), D col = token (lr); packed 8B stores.
    // addr = which*hstr + wdx*9408 + hh*1568 + nn*32 + dd   (chunk-local)
    u32 chpart[2];
    const int chbs[2] = {chb0, chb1};
    #pragma unroll
    for (int n = 0; n < 2; ++n){
      int ch = chbs[n];
      int which = (ch >= 384) ? 2 : ((ch >= 192) ? 1 : 0);
      int rem = ch - which * 192;
      chpart[n] = (u32)which * hstr + (u32)((rem >> 5) * 1568 + (rem & 31));
    }
    #pragma unroll
    for (int m = 0; m < 2; ++m){
      const int t = m0 + wr*32 + m*16 + lr;
      u32 wdx = (u32)t / 49u; u32 tnn = (u32)t - wdx * 49u;
      const u32 rowpart = wdx * 9408u + tnn * 32u;
      #pragma unroll
      for (int n = 0; n < 2; ++n){
        v4u16 pk;
        pk[0] = f2bf(acc[n][m][0]); pk[1] = f2bf(acc[n][m][1]);
        pk[2] = f2bf(acc[n][m][2]); pk[3] = f2bf(acc[n][m][3]);
        *(v4u16*)&ob[chpart[n] + rowpart] = pk;
      }
    }
  } else if (EPI == 1){
    // untransposed: row = token (4*lg+r), col = channel (lr); lane-contiguous
    #pragma unroll
    for (int m = 0; m < 2; ++m){
      #pragma unroll
      for (int r = 0; r < 4; ++r){
        const int gr = m0 + wr*32 + m*16 + lg*4 + r;
        u32 wdx = (u32)gr / 49u; int nn = gr - (int)wdx * 49;
        int bb = (int)(wdx >> 8); int wl = (int)(wdx & 255);
        int wh = wl >> 4, wwi = wl & 15;
        int ii = (int)((u32)nn / 7u), jj = nn - ii * 7;
        int th = wh * 7 + ii + 3;  if (th >= 112) th -= 112;
        int tw = wwi * 7 + jj + 3; if (tw >= 112) tw -= 112;
        u32 adr = (u32)(bb * 12544 + th * 112 + tw) * 192u + (u32)c0;
        of[adr]      = xres[adr]      + acc[m][0][r];
        of[adr + 16] = xres[adr + 16] + acc[m][1][r];
      }
    }
  } else if (EPI == 3){
    // rows already spatial -> linear += (lane-contiguous fp32)
    #pragma unroll
    for (int m = 0; m < 2; ++m){
      #pragma unroll
      for (int r = 0; r < 4; ++r){
        const u32 adr = (u32)(oRowOff + m0 + wr*32 + m*16 + lg*4 + r) * 192u
                        + (u32)c0;
        of[adr]      += acc[m][0][r];
        of[adr + 16] += acc[m][1][r];
      }
    }
  } else {  // EPI == 2: gelu -> h1 bf16, row-linear (chunk-local), lane-contig
    #pragma unroll
    for (int m = 0; m < 2; ++m){
      #pragma unroll
      for (int r = 0; r < 4; ++r){
        const u32 base = (u32)(m0 + wr*32 + m*16 + lg*4 + r) * 768u + (u32)c0;
        float v0 = acc[m][0][r], v1 = acc[m][1][r];
        ob[base]      = f2bf(0.5f * v0 * (1.0f + erff(v0 * 0.7071067811865475f)));
        ob[base + 16] = f2bf(0.5f * v1 * (1.0f + erff(v1 * 0.7071067811865475f)));
      }
    }
  }
}

// ------------------------------- attention (R8 version, chunked) -----------
// one wave per (window, head); 4 waves / block.  49 padded to 64.
// gid chunk-local; wOff = first window of chunk (multiple of 256 -> mask
// class from local index is valid); hstr = chunk q/k/v plane stride.
__global__ __launch_bounds__(256, 4)
void attn_k(const u16* __restrict__ qkv, const float* __restrict__ bmt,
            u16* __restrict__ aout, u32 wOff, u32 hstr){
  __shared__ __align__(16) u16 plds[4][64 * 64];   // 32 KB total
  const int wv = threadIdx.x >> 6, lnn = threadIdx.x & 63;
  const int lr = lnn & 15, lg = lnn >> 4;
  const u32 gid = (u32)blockIdx.x * 4u + (u32)wv;   // chunk-local
  const u32 w = gid / 6u; const int h = (int)(gid - w * 6u);
  const u16* qb = qkv + (size_t)gid * 1568;
  const u16* kb = qb + hstr;
  const u16* vb = kb + hstr;
  const u32 wg = w + wOff;                          // global window

  // C-init = bias+mask table (b128 per lane, L2/L3-resident)
  const int wl = (int)(wg & 255u);
  const int cls = (((wl >> 4) == 15) ? 2 : 0) | (((wl & 15) == 15) ? 1 : 0);
  const float* bmv = bmt + ((u32)(cls * 6 + h) << 12);
  v4f s[4][4];
  #pragma unroll
  for (int m = 0; m < 4; ++m)
    #pragma unroll
    for (int n = 0; n < 4; ++n)
      s[m][n] = *(const v4f*)&bmv[(u32)(((m*4 + n)*16 + lr)*16 + lg*4)];

  // Q.K^T on top of bias
  v8bf aq[4], bk4[4];
  #pragma unroll
  for (int m = 0; m < 4; ++m) aq[m]  = *(const v8bf*)(qb + (m*16 + lr)*32 + lg*8);
  #pragma unroll
  for (int n = 0; n < 4; ++n) bk4[n] = *(const v8bf*)(kb + (n*16 + lr)*32 + lg*8);
  #pragma unroll
  for (int m = 0; m < 4; ++m)
    #pragma unroll
    for (int n = 0; n < 4; ++n) s[m][n] = MFMA16(aq[m], bk4[n], s[m][n]);

  // V fragments from global, k-permuted (pads multiply P==0 -> harmless)
  v8u16 bvu[2][2];
  #pragma unroll
  for (int n2 = 0; n2 < 2; ++n2)
    #pragma unroll
    for (int ksi = 0; ksi < 2; ++ksi)
      #pragma unroll
      for (int e = 0; e < 8; ++e){
        int kp = ksi * 32 + lg * 8 + e;
        int t  = (kp >> 2) + (kp & 3) * 16;
        bvu[n2][ksi][e] = vb[(u32)(t * 32 + n2 * 16 + lr)];
      }

  // P = exp(s), packed store (pos = lr*4+n), XOR-swizzled rows
  #pragma unroll
  for (int m = 0; m < 4; ++m)
    #pragma unroll
    for (int r = 0; r < 4; ++r){
      int row = m*16 + lg*4 + r;
      v4u16 pk;
      pk[0] = f2bf(__expf(s[m][0][r]));
      pk[1] = f2bf(__expf(s[m][1][r]));
      pk[2] = f2bf(__expf(s[m][2][r]));
      pk[3] = f2bf(__expf(s[m][3][r]));
      *(v4u16*)((char*)&plds[wv][0] + row*128 + ((lr*8) ^ ((row & 7) << 4))) = pk;
    }

  v8bf pa[4][2];
  #pragma unroll
  for (int m2 = 0; m2 < 4; ++m2)
    #pragma unroll
    for (int ksi = 0; ksi < 2; ++ksi){
      int row2 = m2*16 + lr;
      pa[m2][ksi] = *(const v8bf*)((const char*)&plds[wv][0] + row2*128 +
                                   ((ksi*64 + lg*16) ^ ((row2 & 7) << 4)));
    }

  // ones B-frag (col 0 only) for row-sums
  v8u16 onesu;
  #pragma unroll
  for (int e = 0; e < 8; ++e) onesu[e] = (lr == 0) ? (u16)0x3F80 : (u16)0;
  const v8bf onesf = __builtin_bit_cast(v8bf, onesu);

  const v4f zf = {0.f, 0.f, 0.f, 0.f};
  v4f o2[4][2], sacc[4];
  #pragma unroll
  for (int m2 = 0; m2 < 4; ++m2){
    o2[m2][0] = zf; o2[m2][1] = zf; sacc[m2] = zf;
  }
  #pragma unroll
  for (int ksi = 0; ksi < 2; ++ksi)
    #pragma unroll
    for (int m2 = 0; m2 < 4; ++m2){
      o2[m2][0] = MFMA16(pa[m2][ksi], __builtin_bit_cast(v8bf, bvu[0][ksi]), o2[m2][0]);
      o2[m2][1] = MFMA16(pa[m2][ksi], __builtin_bit_cast(v8bf, bvu[1][ksi]), o2[m2][1]);
      sacc[m2]  = MFMA16(pa[m2][ksi], onesf, sacc[m2]);
    }

  float inv[4][4];
  #pragma unroll
  for (int m2 = 0; m2 < 4; ++m2)
    #pragma unroll
    for (int r = 0; r < 4; ++r)
      inv[m2][r] = 1.0f / __shfl(sacc[m2][r], lnn & 48, 64);

  #pragma unroll
  for (int m2 = 0; m2 < 4; ++m2){
    #pragma unroll
    for (int n2 = 0; n2 < 2; ++n2){
      #pragma unroll
      for (int r = 0; r < 4; ++r){
        int row = m2*16 + lg*4 + r;
        if (row < 49){
          float val = o2[m2][n2][r] * inv[m2][r];
          aout[(wg * 49u + (u32)row) * 192u + (u32)(h*32 + n2*16 + lr)] = f2bf(val);
        }
      }
    }
  }
}

// ------------------------------ launcher -----------------------------------
extern "C" void kernel_launch(void* const* d_in, const int* in_sizes, int n_in,
                              void* d_out, int out_size, void* d_ws, size_t ws_size,
                              hipStream_t stream){
  const float* x     = (const float*)d_in[0];
  const float* n1g   = (const float*)d_in[1];
  const float* n1b   = (const float*)d_in[2];
  const float* qkvw  = (const float*)d_in[3];
  const float* qkvb  = (const float*)d_in[4];
  const float* rpb   = (const float*)d_in[5];
  const float* projw = (const float*)d_in[6];
  const float* projb = (const float*)d_in[7];
  const float* n2g   = (const float*)d_in[8];
  const float* n2b   = (const float*)d_in[9];
  const float* fc1w  = (const float*)d_in[10];
  const float* fc1b  = (const float*)d_in[11];
  const float* fc2w  = (const float*)d_in[12];
  const float* fc2b  = (const float*)d_in[13];
  float* out = (float*)d_out;

  char* ws  = (char*)d_ws;
  u16* bufA = (u16*)ws;                       // qkv chunk (58MB) / h1 chunk (77MB)
  u16* bufB = (u16*)(ws + 462422016L);        // xw -> attn_out -> xln2
  u16* wq   = (u16*)(ws + 616562688L);
  u16* wp   = wq + 110592;
  u16* w1   = wp + 36864;
  u16* w2   = w1 + 147456;
  float* bmt = (float*)d_out;   // 98304 floats, consumed by attn before proj

  convw<<<1728, 256, 0, stream>>>(qkvw, projw, fc1w, fc2w, wq);
  bmt_k<<<384, 256, 0, stream>>>(rpb, bmt);

  // LN1 + shift + window partition (all rows)
  ln_kern<true><<<25088, 256, 0, stream>>>(x, n1g, n1b, bufB);

  // qkv + attention, L3-blocked: 8 chunks x 1024 windows (50176 rows).
  // qkv chunk buffer = 3 x 9633792 elems (58MB), reused every chunk.
  const u32 HC = 9633792u;                    // 1024*6*49*32
  for (int c = 0; c < 8; ++c){
    const int rowOff = c * 50176;
    gemm_bt<0, 192, 192><<<392*9, 512, 0, stream>>>(bufB, rowOff, wq, 192, 9,
                                                    qkvb, bufA, nullptr,
                                                    nullptr, 0, HC);
    attn_k<<<1536, 256, 0, stream>>>(bufA, bmt, bufB, (u32)(c * 1024), HC);
  }

  // proj (N=192) + scatter + residual -> d_out (spatial order)
  gemm_bt<1, 192, 192><<<3136*3, 512, 0, stream>>>(bufB, 0, wp, 192, 3,
                                                   projb, nullptr, out, x, 0, 0);
  // LN2 (spatial order, linear)
  ln_kern<false><<<25088, 256, 0, stream>>>(out, n2g, n2b, bufB);

  // MLP, L3-blocked: 8 chunks x 50176 tokens; h1 chunk (77MB) reused.
  for (int c = 0; c < 8; ++c){
    const int off = c * 50176;
    gemm_bt<2, 192, 192><<<392*12, 512, 0, stream>>>(bufB, off, w1, 192, 12,
                                                     fc1b, bufA, nullptr,
                                                     nullptr, 0, 0);
    gemm_bt<3, 768, 768><<<392*3, 512, 0, stream>>>(bufA, 0, w2, 768, 3,
                                                    fc2b, nullptr, out,
                                                    nullptr, off, 0);
  }
}

// Round 16
// 1302.862 us; speedup vs baseline: 1.7547x; 1.0353x over previous
//
#include <hip/hip_runtime.h>
#include <stdint.h>
#include <math.h>

// ---------------------------------------------------------------------------
// Swin block, MI355X. B=32 H=W=112 C=192 NH=6 hd=32 WS=7 SS=3 -> 8192 windows,
// 49 tokens, 401408 token-rows.
// R16 = R14 compute kernels (frozen) + FULL L3-blocked pipeline:
//   8 chunks x 1024 windows: ln1->xwC(19MB) -> qkv->qkvC(58MB) ->
//   attn->aoC(19MB) -> proj(scatter+residual -> d_out).
//   8 chunks x 50176 tokens: ln2->xlnC(19MB) -> fc1->h1C(77MB) -> fc2(+=out).
// All chunk buffers reused at the same addresses -> dirty lines overwritten
// in-L3 (write elision) and consumer reads are L3-hits.
// bmt moved from d_out scratch to d_ws (proj now writes d_out mid-loop).
// ---------------------------------------------------------------------------

typedef unsigned short u16;
typedef unsigned int   u32;
typedef __bf16 v8bf __attribute__((ext_vector_type(8)));
typedef float  v4f  __attribute__((ext_vector_type(4)));
typedef u16    v8u16 __attribute__((ext_vector_type(8)));
typedef u16    v4u16 __attribute__((ext_vector_type(4)));

#define MFMA16(a,b,c) __builtin_amdgcn_mfma_f32_16x16x32_bf16(a,b,c,0,0,0)

#define QSC  0.17677669529663687f

__device__ __forceinline__ u16 f2bf(float f){
  return __builtin_bit_cast(u16, (__bf16)f);   // v_cvt RNE
}

__device__ __forceinline__ void async16(void* lds, const void* g){
  __builtin_amdgcn_global_load_lds(
      (__attribute__((address_space(1))) void*)(g),
      (__attribute__((address_space(3))) void*)(lds), 16, 0, 0);
}

// --------------------- combined weight convert (contiguous dst) ------------
// q-rows of qkv_w (first 192*192 elems) pre-scaled by hd^-0.5.
__global__ __launch_bounds__(256)
void convw(const float* __restrict__ s0, const float* __restrict__ s1,
           const float* __restrict__ s2, const float* __restrict__ s3,
           u16* __restrict__ d){
  int i = blockIdx.x * 256 + threadIdx.x;        // < 442368
  float v;
  if (i < 110592){
    v = s0[i];
    if (i < 36864) v *= QSC;
  }
  else if (i < 147456)  v = s1[i - 110592];
  else if (i < 294912)  v = s2[i - 147456];
  else                  v = s3[i - 294912];
  d[i] = f2bf(v);
}

// -------------------- fused rel-pos-bias + shift-mask table ----------------
// layout: [cls][h][m][n][lr][lg*4+r]  (matches MFMA C fragment, b128/lane)
__global__ __launch_bounds__(256)
void bmt_k(const float* __restrict__ rpb, float* __restrict__ bmt){
  int idx = blockIdx.x * 256 + threadIdx.x;      // 98304 total
  int r  = idx & 3, lg = (idx >> 2) & 3, lr = (idx >> 4) & 15;
  int n  = (idx >> 8) & 3, m = (idx >> 10) & 3;
  int t  = idx >> 12; int h = t % 6, cls = t / 6;
  int row = m*16 + lg*4 + r, col = n*16 + lr;
  float v;
  if (row >= 49 || col >= 49){
    v = -1e30f;
  } else {
    int i1 = row / 7, j1 = row - i1 * 7;
    int i2 = col / 7, j2 = col - i2 * 7;
    int ridx = (i1 - i2 + 6) * 13 + (j1 - j2 + 6);
    v = rpb[ridx * 6 + h];
    int lh1 = (cls & 2) ? (i1 < 4 ? 1 : 2) : 0;
    int lw1 = (cls & 1) ? (j1 < 4 ? 1 : 2) : 0;
    int lh2 = (cls & 2) ? (i2 < 4 ? 1 : 2) : 0;
    int lw2 = (cls & 1) ? (j2 < 4 ? 1 : 2) : 0;
    if (lh1 * 3 + lw1 != lh2 * 3 + lw2) v -= 100.f;
  }
  bmt[idx] = v;
}

// ----------------------- LayerNorm (optionally gathered, chunked) ----------
// 16 lanes per token, 4 tokens per wave; lane handles 12 channels (3 float4).
// rowOff = chunk's first global row; output written chunk-locally.
template<bool GATHER>
__global__ __launch_bounds__(256)
void ln_kern(const float* __restrict__ x, const float* __restrict__ g,
             const float* __restrict__ b, u16* __restrict__ o, int rowOff){
  const int ts  = threadIdx.x >> 4;
  const int l16 = threadIdx.x & 15;
  const int rl  = blockIdx.x * 16 + ts;          // chunk-local row
  const int r   = rowOff + rl;                   // global row
  const float* src;
  if (GATHER){
    u32 wdx = (u32)r / 49u; int nn = r - (int)wdx * 49;
    int bb = (int)(wdx >> 8); int wl = (int)(wdx & 255);
    int wh = wl >> 4, wwi = wl & 15;
    int ii = (int)((u32)nn / 7u), jj = nn - ii * 7;
    int th = wh * 7 + ii + 3;  if (th >= 112) th -= 112;
    int tw = wwi * 7 + jj + 3; if (tw >= 112) tw -= 112;
    src = x + (u32)(bb * 12544 + th * 112 + tw) * 192u;
  } else {
    src = x + (u32)r * 192u;
  }
  const float4 a0 = *(const float4*)(src + l16*12);
  const float4 a1 = *(const float4*)(src + l16*12 + 4);
  const float4 a2 = *(const float4*)(src + l16*12 + 8);
  float sm = ((a0.x+a0.y)+(a0.z+a0.w)) + ((a1.x+a1.y)+(a1.z+a1.w))
           + ((a2.x+a2.y)+(a2.z+a2.w));
  float sq = ((a0.x*a0.x+a0.y*a0.y)+(a0.z*a0.z+a0.w*a0.w))
           + ((a1.x*a1.x+a1.y*a1.y)+(a1.z*a1.z+a1.w*a1.w))
           + ((a2.x*a2.x+a2.y*a2.y)+(a2.z*a2.z+a2.w*a2.w));
  #pragma unroll
  for (int d = 1; d < 16; d <<= 1){
    sm += __shfl_xor(sm, d, 64);
    sq += __shfl_xor(sq, d, 64);
  }
  float mean = sm * (1.f/192.f);
  float var  = sq * (1.f/192.f) - mean * mean;
  float rs   = rsqrtf(var + 1e-5f);
  const float4 g0 = *(const float4*)(g + l16*12);
  const float4 g1 = *(const float4*)(g + l16*12 + 4);
  const float4 g2 = *(const float4*)(g + l16*12 + 8);
  const float4 b0 = *(const float4*)(b + l16*12);
  const float4 b1 = *(const float4*)(b + l16*12 + 4);
  const float4 b2 = *(const float4*)(b + l16*12 + 8);
  u16* dst = o + (u32)rl * 192u + l16 * 12;
  v4u16 w0, w1, w2;
  w0[0]=f2bf((a0.x-mean)*rs*g0.x+b0.x); w0[1]=f2bf((a0.y-mean)*rs*g0.y+b0.y);
  w0[2]=f2bf((a0.z-mean)*rs*g0.z+b0.z); w0[3]=f2bf((a0.w-mean)*rs*g0.w+b0.w);
  w1[0]=f2bf((a1.x-mean)*rs*g1.x+b1.x); w1[1]=f2bf((a1.y-mean)*rs*g1.y+b1.y);
  w1[2]=f2bf((a1.z-mean)*rs*g1.z+b1.z); w1[3]=f2bf((a1.w-mean)*rs*g1.w+b1.w);
  w2[0]=f2bf((a2.x-mean)*rs*g2.x+b2.x); w2[1]=f2bf((a2.y-mean)*rs*g2.y+b2.y);
  w2[2]=f2bf((a2.z-mean)*rs*g2.z+b2.z); w2[3]=f2bf((a2.w-mean)*rs*g2.w+b2.w);
  *(v4u16*)(dst)     = w0;
  *(v4u16*)(dst + 4) = w1;
  *(v4u16*)(dst + 8) = w2;
}

// ------------------------------- GEMM (A @ W^T) ----------------------------
// BM=128, BN=64, BK=192/stage, 512 threads = 8 waves, wave = 32x32 quadrant.
// 1D grid, XCD-aligned group swizzle (56 row-blocks x ncol, col-major).
// TRN = (EPI==0): acc[n][m] = mfma(wf, af) -> D[channel][token], packed 8B
// stores (chunk-local qkv, stride hstr). Else acc[m][n] -> D[token][channel].
// EPI: 0 qkv chunk store | 1 proj scatter+residual (global row = oRowOff+m0+..)
//      2 fc1 gelu (chunk-local) | 3 fc2 linear += at global oRowOff
template<int EPI, int LDA, int LDW>
__global__ __launch_bounds__(512)
void gemm_bt(const u16* __restrict__ A, int aRowOff,
             const u16* __restrict__ W, int K, int ncol,
             const float* __restrict__ bias,
             u16* __restrict__ ob, float* __restrict__ of,
             const float* __restrict__ xres, int oRowOff, u32 hstr){
  constexpr bool TRN = (EPI == 0);
  __shared__ __align__(16) u16 sA[128 * 200];
  __shared__ __align__(16) u16 sW[64 * 200];
  const int tid = threadIdx.x;
  const int wv = tid >> 6, lnn = tid & 63;
  const int lr = lnn & 15, lg = lnn >> 4;
  // group swizzle
  const int win = 56 * ncol;
  const int grp = (int)blockIdx.x / win, loc = (int)blockIdx.x - grp * win;
  const int rloc = loc % 56, cblk = loc / 56;
  const int m0   = (grp * 56 + rloc) * 128;
  const int col0 = cblk * 64;
  const int wr = wv >> 1, wc = wv & 1;

  const int c0   = col0 + wc*32 + lr;        // untransposed: channel per lane
  const int chb0 = col0 + wc*32 + lg*4;      // transposed: 4-channel base
  const int chb1 = chb0 + 16;

  v4f acc[2][2];     // TRN: [n][m] channel-major; else [m][n] token-major
  if (TRN){
    float4 bv0 = *(const float4*)&bias[chb0];
    float4 bv1 = *(const float4*)&bias[chb1];
    if (chb0 < 192){ bv0.x*=QSC; bv0.y*=QSC; bv0.z*=QSC; bv0.w*=QSC; }
    if (chb1 < 192){ bv1.x*=QSC; bv1.y*=QSC; bv1.z*=QSC; bv1.w*=QSC; }
    acc[0][0] = acc[0][1] = (v4f){bv0.x, bv0.y, bv0.z, bv0.w};
    acc[1][0] = acc[1][1] = (v4f){bv1.x, bv1.y, bv1.z, bv1.w};
  } else {
    const float b0v = bias[c0];
    const float b1v = bias[c0 + 16];
    #pragma unroll
    for (int m = 0; m < 2; ++m){
      acc[m][0] = (v4f){b0v, b0v, b0v, b0v};
      acc[m][1] = (v4f){b1v, b1v, b1v, b1v};
    }
  }

  const int rA0 = (int)((u32)tid / 25u);
  const int cA0 = tid - rA0 * 25;
  const u32 aBase = (u32)(aRowOff + m0);
  const int nK = K / 192;
  for (int ks = 0; ks < nK; ++ks){
    if (ks) __syncthreads();
    const int k0 = ks * 192;
    // A tile: 128 rows x 25 chunks(16B) = 3200; 6 iters + 128-tail
    int ra = rA0, ca = cA0;
    #pragma unroll
    for (int it = 0; it < 6; ++it){
      int cc = (ca == 24) ? 23 : ca;
      async16((char*)sA + (size_t)(it * 512 + wv * 64) * 16,
              A + (aBase + (u32)ra) * (u32)LDA + (u32)(k0 + cc * 8));
      ra += 20; ca += 12; if (ca >= 25){ ca -= 25; ra += 1; }
    }
    if (tid < 128){
      int cc = (ca == 24) ? 23 : ca;
      async16((char*)sA + (size_t)(3072 + wv * 64) * 16,
              A + (aBase + (u32)ra) * (u32)LDA + (u32)(k0 + cc * 8));
    }
    // W tile: 64 rows x 25 chunks = 1600; 3 iters + 64-tail
    int rw = rA0, cw = cA0;
    #pragma unroll
    for (int it = 0; it < 3; ++it){
      int cc = (cw == 24) ? 23 : cw;
      async16((char*)sW + (size_t)(it * 512 + wv * 64) * 16,
              W + (u32)(col0 + rw) * (u32)LDW + (u32)(k0 + cc * 8));
      rw += 20; cw += 12; if (cw >= 25){ cw -= 25; rw += 1; }
    }
    if (tid < 64){
      int cc = (cw == 24) ? 23 : cw;
      async16((char*)sW + (size_t)1536 * 16,
              W + (u32)(col0 + rw) * (u32)LDW + (u32)(k0 + cc * 8));
    }
    __syncthreads();   // drains vmcnt(0) -> staged data visible

    #pragma unroll
    for (int kk = 0; kk < 6; ++kk){
      v8bf af[2], wf[2];
      #pragma unroll
      for (int m = 0; m < 2; ++m)
        af[m] = *(const v8bf*)&sA[(wr*32 + m*16 + lr) * 200 + kk*32 + lg*8];
      #pragma unroll
      for (int n = 0; n < 2; ++n)
        wf[n] = *(const v8bf*)&sW[(wc*32 + n*16 + lr) * 200 + kk*32 + lg*8];
      if (TRN){
        #pragma unroll
        for (int n = 0; n < 2; ++n)
          #pragma unroll
          for (int m = 0; m < 2; ++m)
            acc[n][m] = MFMA16(wf[n], af[m], acc[n][m]);
      } else {
        #pragma unroll
        for (int m = 0; m < 2; ++m)
          #pragma unroll
          for (int n = 0; n < 2; ++n)
            acc[m][n] = MFMA16(af[m], wf[n], acc[m][n]);
      }
    }
  }

  // ------------------------------ epilogues --------------------------------
  if (EPI == 0){
    // TRN: D row = channel (4*lg+r), D col = token (lr); packed 8B stores.
    // addr = which*hstr + wdx*9408 + hh*1568 + nn*32 + dd   (chunk-local)
    u32 chpart[2];
    const int chbs[2] = {chb0, chb1};
    #pragma unroll
    for (int n = 0; n < 2; ++n){
      int ch = chbs[n];
      int which = (ch >= 384) ? 2 : ((ch >= 192) ? 1 : 0);
      int rem = ch - which * 192;
      chpart[n] = (u32)which * hstr + (u32)((rem >> 5) * 1568 + (rem & 31));
    }
    #pragma unroll
    for (int m = 0; m < 2; ++m){
      const int t = m0 + wr*32 + m*16 + lr;
      u32 wdx = (u32)t / 49u; u32 tnn = (u32)t - wdx * 49u;
      const u32 rowpart = wdx * 9408u + tnn * 32u;
      #pragma unroll
      for (int n = 0; n < 2; ++n){
        v4u16 pk;
        pk[0] = f2bf(acc[n][m][0]); pk[1] = f2bf(acc[n][m][1]);
        pk[2] = f2bf(acc[n][m][2]); pk[3] = f2bf(acc[n][m][3]);
        *(v4u16*)&ob[chpart[n] + rowpart] = pk;
      }
    }
  } else if (EPI == 1){
    // global row = oRowOff + local; window->spatial scatter + residual
    #pragma unroll
    for (int m = 0; m < 2; ++m){
      #pragma unroll
      for (int r = 0; r < 4; ++r){
        const int gr = oRowOff + m0 + wr*32 + m*16 + lg*4 + r;
        u32 wdx = (u32)gr / 49u; int nn = gr - (int)wdx * 49;
        int bb = (int)(wdx >> 8); int wl = (int)(wdx & 255);
        int wh = wl >> 4, wwi = wl & 15;
        int ii = (int)((u32)nn / 7u), jj = nn - ii * 7;
        int th = wh * 7 + ii + 3;  if (th >= 112) th -= 112;
        int tw = wwi * 7 + jj + 3; if (tw >= 112) tw -= 112;
        u32 adr = (u32)(bb * 12544 + th * 112 + tw) * 192u + (u32)c0;
        of[adr]      = xres[adr]      + acc[m][0][r];
        of[adr + 16] = xres[adr + 16] + acc[m][1][r];
      }
    }
  } else if (EPI == 3){
    // rows already spatial -> linear += at global oRowOff (lane-contiguous)
    #pragma unroll
    for (int m = 0; m < 2; ++m){
      #pragma unroll
      for (int r = 0; r < 4; ++r){
        const u32 adr = (u32)(oRowOff + m0 + wr*32 + m*16 + lg*4 + r) * 192u
                        + (u32)c0;
        of[adr]      += acc[m][0][r];
        of[adr + 16] += acc[m][1][r];
      }
    }
  } else {  // EPI == 2: gelu -> h1 chunk-local bf16, lane-contiguous
    #pragma unroll
    for (int m = 0; m < 2; ++m){
      #pragma unroll
      for (int r = 0; r < 4; ++r){
        const u32 base = (u32)(m0 + wr*32 + m*16 + lg*4 + r) * 768u + (u32)c0;
        float v0 = acc[m][0][r], v1 = acc[m][1][r];
        ob[base]      = f2bf(0.5f * v0 * (1.0f + erff(v0 * 0.7071067811865475f)));
        ob[base + 16] = f2bf(0.5f * v1 * (1.0f + erff(v1 * 0.7071067811865475f)));
      }
    }
  }
}

// ------------------------------- attention (chunk-local I/O) ---------------
// one wave per (window, head); 4 waves / block.  49 padded to 64.
// gid chunk-local; wOff (mult of 256) used only for the mask class; aout is
// the chunk-local buffer (written at local window index).
__global__ __launch_bounds__(256, 4)
void attn_k(const u16* __restrict__ qkv, const float* __restrict__ bmt,
            u16* __restrict__ aout, u32 wOff, u32 hstr){
  __shared__ __align__(16) u16 plds[4][64 * 64];   // 32 KB total
  const int wv = threadIdx.x >> 6, lnn = threadIdx.x & 63;
  const int lr = lnn & 15, lg = lnn >> 4;
  const u32 gid = (u32)blockIdx.x * 4u + (u32)wv;   // chunk-local
  const u32 w = gid / 6u; const int h = (int)(gid - w * 6u);
  const u16* qb = qkv + (size_t)gid * 1568;
  const u16* kb = qb + hstr;
  const u16* vb = kb + hstr;
  const u32 wg = w + wOff;                          // global window (mask only)

  // C-init = bias+mask table (b128 per lane, L2/L3-resident)
  const int wl = (int)(wg & 255u);
  const int cls = (((wl >> 4) == 15) ? 2 : 0) | (((wl & 15) == 15) ? 1 : 0);
  const float* bmv = bmt + ((u32)(cls * 6 + h) << 12);
  v4f s[4][4];
  #pragma unroll
  for (int m = 0; m < 4; ++m)
    #pragma unroll
    for (int n = 0; n < 4; ++n)
      s[m][n] = *(const v4f*)&bmv[(u32)(((m*4 + n)*16 + lr)*16 + lg*4)];

  // Q.K^T on top of bias
  v8bf aq[4], bk4[4];
  #pragma unroll
  for (int m = 0; m < 4; ++m) aq[m]  = *(const v8bf*)(qb + (m*16 + lr)*32 + lg*8);
  #pragma unroll
  for (int n = 0; n < 4; ++n) bk4[n] = *(const v8bf*)(kb + (n*16 + lr)*32 + lg*8);
  #pragma unroll
  for (int m = 0; m < 4; ++m)
    #pragma unroll
    for (int n = 0; n < 4; ++n) s[m][n] = MFMA16(aq[m], bk4[n], s[m][n]);

  // V fragments from global, k-permuted (pads multiply P==0 -> harmless)
  v8u16 bvu[2][2];
  #pragma unroll
  for (int n2 = 0; n2 < 2; ++n2)
    #pragma unroll
    for (int ksi = 0; ksi < 2; ++ksi)
      #pragma unroll
      for (int e = 0; e < 8; ++e){
        int kp = ksi * 32 + lg * 8 + e;
        int t  = (kp >> 2) + (kp & 3) * 16;
        bvu[n2][ksi][e] = vb[(u32)(t * 32 + n2 * 16 + lr)];
      }

  // P = exp(s), packed store (pos = lr*4+n), XOR-swizzled rows
  #pragma unroll
  for (int m = 0; m < 4; ++m)
    #pragma unroll
    for (int r = 0; r < 4; ++r){
      int row = m*16 + lg*4 + r;
      v4u16 pk;
      pk[0] = f2bf(__expf(s[m][0][r]));
      pk[1] = f2bf(__expf(s[m][1][r]));
      pk[2] = f2bf(__expf(s[m][2][r]));
      pk[3] = f2bf(__expf(s[m][3][r]));
      *(v4u16*)((char*)&plds[wv][0] + row*128 + ((lr*8) ^ ((row & 7) << 4))) = pk;
    }

  v8bf pa[4][2];
  #pragma unroll
  for (int m2 = 0; m2 < 4; ++m2)
    #pragma unroll
    for (int ksi = 0; ksi < 2; ++ksi){
      int row2 = m2*16 + lr;
      pa[m2][ksi] = *(const v8bf*)((const char*)&plds[wv][0] + row2*128 +
                                   ((ksi*64 + lg*16) ^ ((row2 & 7) << 4)));
    }

  // ones B-frag (col 0 only) for row-sums
  v8u16 onesu;
  #pragma unroll
  for (int e = 0; e < 8; ++e) onesu[e] = (lr == 0) ? (u16)0x3F80 : (u16)0;
  const v8bf onesf = __builtin_bit_cast(v8bf, onesu);

  const v4f zf = {0.f, 0.f, 0.f, 0.f};
  v4f o2[4][2], sacc[4];
  #pragma unroll
  for (int m2 = 0; m2 < 4; ++m2){
    o2[m2][0] = zf; o2[m2][1] = zf; sacc[m2] = zf;
  }
  #pragma unroll
  for (int ksi = 0; ksi < 2; ++ksi)
    #pragma unroll
    for (int m2 = 0; m2 < 4; ++m2){
      o2[m2][0] = MFMA16(pa[m2][ksi], __builtin_bit_cast(v8bf, bvu[0][ksi]), o2[m2][0]);
      o2[m2][1] = MFMA16(pa[m2][ksi], __builtin_bit_cast(v8bf, bvu[1][ksi]), o2[m2][1]);
      sacc[m2]  = MFMA16(pa[m2][ksi], onesf, sacc[m2]);
    }

  float inv[4][4];
  #pragma unroll
  for (int m2 = 0; m2 < 4; ++m2)
    #pragma unroll
    for (int r = 0; r < 4; ++r)
      inv[m2][r] = 1.0f / __shfl(sacc[m2][r], lnn & 48, 64);

  #pragma unroll
  for (int m2 = 0; m2 < 4; ++m2){
    #pragma unroll
    for (int n2 = 0; n2 < 2; ++n2){
      #pragma unroll
      for (int r = 0; r < 4; ++r){
        int row = m2*16 + lg*4 + r;
        if (row < 49){
          float val = o2[m2][n2][r] * inv[m2][r];
          aout[(w * 49u + (u32)row) * 192u + (u32)(h*32 + n2*16 + lr)] = f2bf(val);
        }
      }
    }
  }
}

// ------------------------------ launcher -----------------------------------
extern "C" void kernel_launch(void* const* d_in, const int* in_sizes, int n_in,
                              void* d_out, int out_size, void* d_ws, size_t ws_size,
                              hipStream_t stream){
  const float* x     = (const float*)d_in[0];
  const float* n1g   = (const float*)d_in[1];
  const float* n1b   = (const float*)d_in[2];
  const float* qkvw  = (const float*)d_in[3];
  const float* qkvb  = (const float*)d_in[4];
  const float* rpb   = (const float*)d_in[5];
  const float* projw = (const float*)d_in[6];
  const float* projb = (const float*)d_in[7];
  const float* n2g   = (const float*)d_in[8];
  const float* n2b   = (const float*)d_in[9];
  const float* fc1w  = (const float*)d_in[10];
  const float* fc1b  = (const float*)d_in[11];
  const float* fc2w  = (const float*)d_in[12];
  const float* fc2b  = (const float*)d_in[13];
  float* out = (float*)d_out;

  // ws layout (all chunk buffers reused; everything < 122MB of >=617MB ws):
  char* ws   = (char*)d_ws;
  u16* bigC  = (u16*)ws;                      // qkvC 58MB / h1C 77MB
  u16* xwC   = (u16*)(ws + 80000000L);        // 19.3MB (xw / xln2 chunk)
  u16* aoC   = (u16*)(ws + 100000000L);       // 19.3MB (attn out chunk)
  float* bmt = (float*)(ws + 120000000L);     // 0.4MB
  u16* wq    = (u16*)(ws + 121000000L);       // 0.9MB weights
  u16* wp    = wq + 110592;
  u16* w1    = wp + 36864;
  u16* w2    = w1 + 147456;

  convw<<<1728, 256, 0, stream>>>(qkvw, projw, fc1w, fc2w, wq);
  bmt_k<<<384, 256, 0, stream>>>(rpb, bmt);

  // attention pipeline, L3-blocked: 8 chunks x 1024 windows (50176 rows)
  const u32 HC = 9633792u;                    // 1024*6*49*32
  for (int c = 0; c < 8; ++c){
    const int rowOff = c * 50176;
    // LN1 + shift + window partition -> xwC (chunk-local)
    ln_kern<true><<<3136, 256, 0, stream>>>(x, n1g, n1b, xwC, rowOff);
    // qkv -> qkvC
    gemm_bt<0, 192, 192><<<392*9, 512, 0, stream>>>(xwC, 0, wq, 192, 9,
                                                    qkvb, bigC, nullptr,
                                                    nullptr, 0, HC);
    // attention -> aoC
    attn_k<<<1536, 256, 0, stream>>>(bigC, bmt, aoC, (u32)(c * 1024), HC);
    // proj + scatter + residual -> d_out (global rows rowOff..)
    gemm_bt<1, 192, 192><<<392*3, 512, 0, stream>>>(aoC, 0, wp, 192, 3,
                                                    projb, nullptr, out,
                                                    x, rowOff, 0);
  }

  // MLP, L3-blocked: 8 chunks x 50176 tokens
  for (int c = 0; c < 8; ++c){
    const int off = c * 50176;
    // LN2 (linear) -> xwC (reused as xln2 chunk)
    ln_kern<false><<<3136, 256, 0, stream>>>(out, n2g, n2b, xwC, off);
    // fc1 + gelu -> h1C
    gemm_bt<2, 192, 192><<<392*12, 512, 0, stream>>>(xwC, 0, w1, 192, 12,
                                                     fc1b, bigC, nullptr,
                                                     nullptr, 0, 0);
    // fc2 += out (global rows off..)
    gemm_bt<3, 768, 768><<<392*3, 512, 0, stream>>>(bigC, 0, w2, 768, 3,
                                                    fc2b, nullptr, out,
                                                    nullptr, off, 0);
  }
}